// Round 2
// baseline (650.231 us; speedup 1.0000x reference)
//
#include <hip/hip_runtime.h>
#include <stdint.h>

typedef short bf16x8 __attribute__((ext_vector_type(8)));
typedef float f32x4 __attribute__((ext_vector_type(4)));

#define DEVINL static __device__ __forceinline__

DEVINL unsigned short f2bf(float f) {
    union { float f; uint32_t u; } v; v.f = f;
    return (unsigned short)((v.u + 0x7FFFu + ((v.u >> 16) & 1u)) >> 16);
}
DEVINL float bf2f(unsigned short b) {
    union { uint32_t u; float f; } v; v.u = ((uint32_t)b) << 16;
    return v.f;
}

DEVINL void load_lds16(const void* g, void* l) {
    __builtin_amdgcn_global_load_lds(
        (const __attribute__((address_space(1))) void*)g,
        (__attribute__((address_space(3))) void*)l, 16, 0, 0);
}

// ---------------- f32 -> bf16 convert ----------------
__global__ __launch_bounds__(256) void k_cvt(const float* __restrict__ src,
                                             unsigned short* __restrict__ dst, int n4) {
    int stride = gridDim.x * blockDim.x;
    for (int i = blockIdx.x * blockDim.x + threadIdx.x; i < n4; i += stride) {
        float4 f = reinterpret_cast<const float4*>(src)[i];
        ushort4 o;
        o.x = f2bf(f.x); o.y = f2bf(f.y); o.z = f2bf(f.z); o.w = f2bf(f.w);
        reinterpret_cast<ushort4*>(dst)[i] = o;
    }
}

// ---------------- f32 -> bf16 hi/lo split convert ----------------
__global__ __launch_bounds__(256) void k_cvt_hl(const float* __restrict__ src,
                                                unsigned short* __restrict__ hi,
                                                unsigned short* __restrict__ lo, int n4) {
    int stride = gridDim.x * blockDim.x;
    for (int i = blockIdx.x * blockDim.x + threadIdx.x; i < n4; i += stride) {
        float4 f = reinterpret_cast<const float4*>(src)[i];
        ushort4 h, l;
        h.x = f2bf(f.x); l.x = f2bf(f.x - bf2f(h.x));
        h.y = f2bf(f.y); l.y = f2bf(f.y - bf2f(h.y));
        h.z = f2bf(f.z); l.z = f2bf(f.z - bf2f(h.z));
        h.w = f2bf(f.w); l.w = f2bf(f.w - bf2f(h.w));
        reinterpret_cast<ushort4*>(hi)[i] = h;
        reinterpret_cast<ushort4*>(lo)[i] = l;
    }
}

// ---------------- NT GEMM: C[M,N] = A[M,K] * B[N,K]^T (+ C if ACCUM) ----------------
// K = N = 1024 fixed. 128x128 tile, 4 waves, 16x16x32 bf16 MFMA,
// global_load_lds width-16 staging, double-buffered LDS, 2-phase loop.
template<int OUT_BF16, int HAS_BIAS, int ACCUM>
__global__ __launch_bounds__(256) void k_gemm(
    const unsigned short* __restrict__ A,
    const unsigned short* __restrict__ B,
    void* __restrict__ Cout,
    const float* __restrict__ bias, int M)
{
    constexpr int K = 1024;
    constexpr int N = 1024;
    __shared__ __align__(16) unsigned short Al[2][128 * 32];
    __shared__ __align__(16) unsigned short Bl[2][128 * 32];

    const int m0 = blockIdx.y * 128;
    const int n0 = blockIdx.x * 128;
    const int tid = threadIdx.x;
    const int w = tid >> 6;
    const int lane = tid & 63;
    const int wm = w & 1;
    const int wn = w >> 1;

    const int srow = lane >> 2;  // row within 16-row chunk
    const int sseg = lane & 3;   // 16B segment within 64B row

    f32x4 acc[4][4] = {};

    const size_t a_base = (size_t)m0 * K;
    const size_t b_base = (size_t)n0 * K;

    auto stage = [&](int buf, int kt) {
        const int k0 = kt * 32;
        #pragma unroll
        for (int j = 0; j < 2; ++j) {
            const int chunk = w * 2 + j;
            const int row = chunk * 16 + srow;
            load_lds16(A + a_base + (size_t)row * K + k0 + sseg * 8, &Al[buf][chunk * 512]);
            load_lds16(B + b_base + (size_t)row * K + k0 + sseg * 8, &Bl[buf][chunk * 512]);
        }
    };

    stage(0, 0);
    __syncthreads();

    int cur = 0;
    for (int kt = 0; kt < K / 32; ++kt) {
        if (kt + 1 < K / 32) stage(cur ^ 1, kt + 1);
        const unsigned short* As = &Al[cur][0];
        const unsigned short* Bs = &Bl[cur][0];
        bf16x8 af[4], bfr[4];
        #pragma unroll
        for (int i = 0; i < 4; ++i)
            af[i] = *reinterpret_cast<const bf16x8*>(
                As + (wm * 64 + i * 16 + (lane & 15)) * 32 + (lane >> 4) * 8);
        #pragma unroll
        for (int j = 0; j < 4; ++j)
            bfr[j] = *reinterpret_cast<const bf16x8*>(
                Bs + (wn * 64 + j * 16 + (lane & 15)) * 32 + (lane >> 4) * 8);
        #pragma unroll
        for (int i = 0; i < 4; ++i)
            #pragma unroll
            for (int j = 0; j < 4; ++j)
                acc[i][j] = __builtin_amdgcn_mfma_f32_16x16x32_bf16(af[i], bfr[j], acc[i][j], 0, 0, 0);
        __syncthreads();
        cur ^= 1;
    }

    // epilogue: C/D layout col=lane&15, row=(lane>>4)*4+r
    const int cl = lane & 15;
    const int rg = lane >> 4;
    #pragma unroll
    for (int j = 0; j < 4; ++j) {
        const int col = n0 + wn * 64 + j * 16 + cl;
        const float bv = HAS_BIAS ? bias[col] : 0.f;
        #pragma unroll
        for (int i = 0; i < 4; ++i) {
            const int row0 = m0 + wm * 64 + i * 16 + rg * 4;
            #pragma unroll
            for (int r = 0; r < 4; ++r) {
                float val = acc[i][j][r] + bv;
                const size_t off = (size_t)(row0 + r) * N + col;
                if (ACCUM) val += reinterpret_cast<float*>(Cout)[off];
                if (OUT_BF16) reinterpret_cast<unsigned short*>(Cout)[off] = f2bf(val);
                else          reinterpret_cast<float*>(Cout)[off] = val;
            }
        }
    }
}

// ---------------- per-token HxH attention, one wave per token, full f32 ----------------
// qp: bf16 [32768][1024], kp: f32 [8192][1024], vp: bf16 [8192][1024].
// LN (gamma,beta,eps=1e-5) on q (x0.125) and k, all f32.
// S = qln*kln^T (16x16), softmax over g, x = P*v (16x64), bf16 scrambled store:
// x_scr[b, h*128+n/16, (n%16)*64+d]
__global__ __launch_bounds__(256) void k_attn(
    const unsigned short* __restrict__ qp,
    const float* __restrict__ kp,
    const unsigned short* __restrict__ vp,
    const float* __restrict__ gamma,
    const float* __restrict__ beta,
    unsigned short* __restrict__ xout)
{
    __shared__ float ks[4][16 * 64];
    __shared__ float vs[4][16 * 64];

    const int w = threadIdx.x >> 6;
    const int lane = threadIdx.x & 63;
    const int token = blockIdx.x * 4 + w;   // grid covers exactly 32768 tokens
    const int b = token >> 11;
    const int n = token & 2047;
    const int kb = b & 3;

    const int h = lane >> 2;    // head / row 0..15
    const int qd = lane & 3;    // quarter of head_dim
    const int d0 = qd * 16;

    const unsigned short* qptr = qp + (size_t)token * 1024 + h * 64 + d0;
    const float*          kptr = kp + (size_t)(kb * 2048 + n) * 1024 + h * 64 + d0;
    const unsigned short* vptr = vp + (size_t)(kb * 2048 + n) * 1024 + h * 64 + d0;

    float gm[16], bt[16];
    #pragma unroll
    for (int t = 0; t < 16; ++t) { gm[t] = gamma[d0 + t]; bt[t] = beta[d0 + t]; }

    // ---- load q (bf16), LN in f32, scale 0.125 -> yq regs ----
    float yq[16];
    {
        const uint4* p = reinterpret_cast<const uint4*>(qptr);
        const uint4 u0 = p[0], u1 = p[1];
        const uint32_t uu[8] = {u0.x, u0.y, u0.z, u0.w, u1.x, u1.y, u1.z, u1.w};
        float x[16]; float s = 0.f, sq = 0.f;
        #pragma unroll
        for (int t = 0; t < 8; ++t) {
            const float a = bf2f((unsigned short)(uu[t] & 0xffffu));
            const float c = bf2f((unsigned short)(uu[t] >> 16));
            x[2 * t] = a; x[2 * t + 1] = c;
            s += a + c; sq += a * a + c * c;
        }
        s  += __shfl_xor(s, 1);  s  += __shfl_xor(s, 2);
        sq += __shfl_xor(sq, 1); sq += __shfl_xor(sq, 2);
        const float mu = s * 0.015625f;
        const float var = sq * 0.015625f - mu * mu;
        const float inv = rsqrtf(var + 1e-5f);
        #pragma unroll
        for (int t = 0; t < 16; ++t)
            yq[t] = ((x[t] - mu) * inv * gm[t] + bt[t]) * 0.125f;
    }

    // ---- load k (f32), LN in f32 -> ks LDS ----
    {
        const float4* p = reinterpret_cast<const float4*>(kptr);
        const float4 f0 = p[0], f1 = p[1], f2 = p[2], f3 = p[3];
        float x[16] = {f0.x, f0.y, f0.z, f0.w, f1.x, f1.y, f1.z, f1.w,
                       f2.x, f2.y, f2.z, f2.w, f3.x, f3.y, f3.z, f3.w};
        float s = 0.f, sq = 0.f;
        #pragma unroll
        for (int t = 0; t < 16; ++t) { s += x[t]; sq += x[t] * x[t]; }
        s  += __shfl_xor(s, 1);  s  += __shfl_xor(s, 2);
        sq += __shfl_xor(sq, 1); sq += __shfl_xor(sq, 2);
        const float mu = s * 0.015625f;
        const float var = sq * 0.015625f - mu * mu;
        const float inv = rsqrtf(var + 1e-5f);
        #pragma unroll
        for (int t = 0; t < 16; ++t)
            ks[w][h * 64 + d0 + t] = (x[t] - mu) * inv * gm[t] + bt[t];
    }

    // ---- load v (bf16) -> vs LDS (f32) ----
    {
        const uint4* p = reinterpret_cast<const uint4*>(vptr);
        const uint4 u0 = p[0], u1 = p[1];
        const uint32_t uu[8] = {u0.x, u0.y, u0.z, u0.w, u1.x, u1.y, u1.z, u1.w};
        #pragma unroll
        for (int t = 0; t < 8; ++t) {
            vs[w][h * 64 + d0 + 2 * t]     = bf2f((unsigned short)(uu[t] & 0xffffu));
            vs[w][h * 64 + d0 + 2 * t + 1] = bf2f((unsigned short)(uu[t] >> 16));
        }
    }
    __syncthreads();

    // ---- S[h][g] = sum_d yq[h][d]*kln[g][d]; partial over this lane's 16 d's,
    //      then butterfly over the 4 qd lanes (bit-identical across the group) ----
    float S[16];
    #pragma unroll
    for (int g = 0; g < 16; ++g) {
        float p = 0.f;
        #pragma unroll
        for (int t = 0; t < 16; ++t) p += yq[t] * ks[w][g * 64 + d0 + t];
        p += __shfl_xor(p, 1);
        p += __shfl_xor(p, 2);
        S[g] = p;
    }

    // ---- softmax over g, replicated per lane (no cross-lane needed) ----
    float m = S[0];
    #pragma unroll
    for (int g = 1; g < 16; ++g) m = fmaxf(m, S[g]);
    float sum = 0.f;
    #pragma unroll
    for (int g = 0; g < 16; ++g) { S[g] = __expf(S[g] - m); sum += S[g]; }
    const float rs = 1.f / sum;
    #pragma unroll
    for (int g = 0; g < 16; ++g) S[g] *= rs;

    // ---- x[h][d] = sum_g P[g]*v[g][d] for this lane's 16 d's ----
    float xo[16] = {};
    #pragma unroll
    for (int g = 0; g < 16; ++g) {
        const float pg = S[g];
        #pragma unroll
        for (int t = 0; t < 16; ++t) xo[t] += pg * vs[w][g * 64 + d0 + t];
    }

    // ---- bf16 scrambled store: row = h*128 + n/16, col = (n%16)*64 + d ----
    const size_t obase = (size_t)b * 2048 * 1024;
    const int row = h * 128 + (n >> 4);
    const int col = (n & 15) * 64 + d0;
    uint32_t pk[8];
    #pragma unroll
    for (int t = 0; t < 8; ++t)
        pk[t] = (uint32_t)f2bf(xo[2 * t]) | ((uint32_t)f2bf(xo[2 * t + 1]) << 16);
    uint4* dst = reinterpret_cast<uint4*>(xout + obase + (size_t)row * 1024 + col);
    uint4 lo; lo.x = pk[0]; lo.y = pk[1]; lo.z = pk[2]; lo.w = pk[3];
    uint4 hi; hi.x = pk[4]; hi.y = pk[5]; hi.z = pk[6]; hi.w = pk[7];
    dst[0] = lo; dst[1] = hi;
}

extern "C" void kernel_launch(void* const* d_in, const int* in_sizes, int n_in,
                              void* d_out, int out_size, void* d_ws, size_t ws_size,
                              hipStream_t stream) {
    const float* q     = (const float*)d_in[0];
    const float* k     = (const float*)d_in[1];
    const float* v     = (const float*)d_in[2];
    const float* Wq    = (const float*)d_in[3];
    const float* Wk    = (const float*)d_in[4];
    const float* Wv    = (const float*)d_in[5];
    const float* Wo    = (const float*)d_in[6];
    const float* bo    = (const float*)d_in[7];
    const float* gamma = (const float*)d_in[8];
    const float* beta  = (const float*)d_in[9];
    float* out = (float*)d_out;

    char* ws = (char*)d_ws;
    const size_t MB = 1024 * 1024;
    // [0,64):    qb (bf16 q input) -> later xsc (bf16 scrambled attn out)
    // [64,128):  qpb (bf16 q-proj out)
    // [128,160): kpf (f32 k-proj out)
    // [160,176): vpb (bf16 v-proj out)
    // [176,192): kbb (bf16 k input) -> later vbb (bf16 v input)
    // [192,194): W hi slot (bf16, reused)
    // [194,196): W lo slot (bf16, reused)
    unsigned short* qb   = (unsigned short*)(ws + 0);
    unsigned short* xsc  = (unsigned short*)(ws + 0);
    unsigned short* qpb  = (unsigned short*)(ws + 64 * MB);
    float*          kpf  = (float*)         (ws + 128 * MB);
    unsigned short* vpb  = (unsigned short*)(ws + 160 * MB);
    unsigned short* kbb  = (unsigned short*)(ws + 176 * MB);
    unsigned short* vbb  = (unsigned short*)(ws + 176 * MB);
    unsigned short* Whi  = (unsigned short*)(ws + 192 * MB);
    unsigned short* Wlo  = (unsigned short*)(ws + 194 * MB);

    // ---- k path: split-Wk two-pass into f32 kpf ----
    k_cvt_hl<<<1024, 256, 0, stream>>>(Wk, Whi, Wlo, 262144);
    k_cvt<<<1024, 256, 0, stream>>>(k, kbb, 2097152);
    k_gemm<0, 0, 0><<<dim3(8, 64), 256, 0, stream>>>(kbb, Whi, kpf, nullptr, 8192);
    k_gemm<0, 0, 1><<<dim3(8, 64), 256, 0, stream>>>(kbb, Wlo, kpf, nullptr, 8192);

    // ---- v path: plain bf16 ---- (vbb overwrites kbb region: k-proj done)
    k_cvt<<<1024, 256, 0, stream>>>(Wv, Whi, 262144);
    k_cvt<<<1024, 256, 0, stream>>>(v, vbb, 2097152);
    k_gemm<1, 0, 0><<<dim3(8, 64), 256, 0, stream>>>(vbb, Whi, vpb, nullptr, 8192);

    // ---- q path: plain bf16 ----
    k_cvt<<<1024, 256, 0, stream>>>(Wq, Whi, 262144);
    k_cvt<<<2048, 256, 0, stream>>>(q, qb, 8388608);
    k_gemm<1, 0, 0><<<dim3(8, 256), 256, 0, stream>>>(qb, Whi, qpb, nullptr, 32768);

    // ---- attention (full f32 middle), writes scrambled bf16 over qb region ----
    k_attn<<<8192, 256, 0, stream>>>(qpb, kpf, vpb, gamma, beta, xsc);

    // ---- out path: split-Wo two-pass, f32 + bias into d_out ----
    k_cvt_hl<<<1024, 256, 0, stream>>>(Wo, Whi, Wlo, 262144);
    k_gemm<0, 1, 0><<<dim3(8, 256), 256, 0, stream>>>(xsc, Whi, out, bo, 32768);
    k_gemm<0, 0, 1><<<dim3(8, 256), 256, 0, stream>>>(xsc, Wlo, out, nullptr, 32768);
}

// Round 3
// 471.427 us; speedup vs baseline: 1.3793x; 1.3793x over previous
//
#include <hip/hip_runtime.h>
#include <stdint.h>

typedef short bf16x8 __attribute__((ext_vector_type(8)));
typedef float f32x4 __attribute__((ext_vector_type(4)));

#define DEVINL static __device__ __forceinline__

DEVINL unsigned short f2bf(float f) {
    union { float f; uint32_t u; } v; v.f = f;
    return (unsigned short)((v.u + 0x7FFFu + ((v.u >> 16) & 1u)) >> 16);
}
DEVINL float bf2f(unsigned short b) {
    union { uint32_t u; float f; } v; v.u = ((uint32_t)b) << 16;
    return v.f;
}

DEVINL void load_lds16(const void* g, void* l) {
    __builtin_amdgcn_global_load_lds(
        (const __attribute__((address_space(1))) void*)g,
        (__attribute__((address_space(3))) void*)l, 16, 0, 0);
}

// ---------------- f32 -> bf16 convert ----------------
__global__ __launch_bounds__(256) void k_cvt(const float* __restrict__ src,
                                             unsigned short* __restrict__ dst, int n4) {
    int stride = gridDim.x * blockDim.x;
    for (int i = blockIdx.x * blockDim.x + threadIdx.x; i < n4; i += stride) {
        float4 f = reinterpret_cast<const float4*>(src)[i];
        ushort4 o;
        o.x = f2bf(f.x); o.y = f2bf(f.y); o.z = f2bf(f.z); o.w = f2bf(f.w);
        reinterpret_cast<ushort4*>(dst)[i] = o;
    }
}

// ---------------- f32 -> bf16 hi/lo split convert ----------------
__global__ __launch_bounds__(256) void k_cvt_hl(const float* __restrict__ src,
                                                unsigned short* __restrict__ hi,
                                                unsigned short* __restrict__ lo, int n4) {
    int stride = gridDim.x * blockDim.x;
    for (int i = blockIdx.x * blockDim.x + threadIdx.x; i < n4; i += stride) {
        float4 f = reinterpret_cast<const float4*>(src)[i];
        ushort4 h, l;
        h.x = f2bf(f.x); l.x = f2bf(f.x - bf2f(h.x));
        h.y = f2bf(f.y); l.y = f2bf(f.y - bf2f(h.y));
        h.z = f2bf(f.z); l.z = f2bf(f.z - bf2f(h.z));
        h.w = f2bf(f.w); l.w = f2bf(f.w - bf2f(h.w));
        reinterpret_cast<ushort4*>(hi)[i] = h;
        reinterpret_cast<ushort4*>(lo)[i] = l;
    }
}

// ---------------- NT GEMM: C[M,N] = A * Bh^T (+ A * Bl^T if DUAL) ----------------
// K = N = 1024 fixed. 128x128 tile, 4 waves, 16x16x32 bf16 MFMA.
// global_load_lds width-16 staging (LDS linear, source k-seg pre-swizzled),
// swizzled ds_read (conflict-free), double-buffered LDS, XCD-aware block swizzle.
template<int OUT_BF16, int HAS_BIAS, int DUAL>
__global__ __launch_bounds__(256) void k_gemm(
    const unsigned short* __restrict__ A,
    const unsigned short* __restrict__ Bh,
    const unsigned short* __restrict__ Bl,
    void* __restrict__ Cout,
    const float* __restrict__ bias, int M)
{
    constexpr int K = 1024;
    constexpr int N = 1024;
    // LDS: A | Bh | (Bl if DUAL), each double-buffered [2][128*32] ushorts
    __shared__ __align__(16) unsigned short smem[(DUAL ? 6 : 4) * 4096];
    unsigned short* Al  = smem;
    unsigned short* Bhl = smem + 2 * 4096;
    unsigned short* Bll = DUAL ? smem + 4 * 4096 : nullptr;

    // ---- T1: XCD-aware block swizzle (nwg % 8 == 0 always here) ----
    const int nwg = gridDim.x;
    const int bid = blockIdx.x;
    const int wg = (bid & 7) * (nwg >> 3) + (bid >> 3);
    const int m0 = (wg >> 3) * 128;      // 8 n-tiles per m-panel (N=1024)
    const int n0 = (wg & 7) * 128;

    const int tid = threadIdx.x;
    const int w = tid >> 6;
    const int lane = tid & 63;
    const int wm = w & 1;
    const int wn = w >> 1;

    const int srow = lane >> 2;                       // row within 16-row chunk
    const int sseg = lane & 3;                        // 16B segment within 64B row
    const int sslot = sseg ^ ((srow >> 1) & 3);       // pre-swizzled source k-seg

    f32x4 acc[4][4] = {};
    f32x4 acl[4][4] = {};

    const size_t a_base = (size_t)m0 * K;
    const size_t b_base = (size_t)n0 * K;

    auto stage = [&](int buf, int kt) {
        const int k0 = kt * 32;
        #pragma unroll
        for (int j = 0; j < 2; ++j) {
            const int chunk = w * 2 + j;
            const int row = chunk * 16 + srow;
            const size_t goff = (size_t)row * K + k0 + sslot * 8;
            load_lds16(A + a_base + goff, Al + buf * 4096 + chunk * 512);
            load_lds16(Bh + b_base + goff, Bhl + buf * 4096 + chunk * 512);
            if (DUAL) load_lds16(Bl + b_base + goff, Bll + buf * 4096 + chunk * 512);
        }
    };

    stage(0, 0);
    __syncthreads();

    const int rr = lane & 15;
    const int slot8 = ((lane >> 4) ^ ((rr >> 1) & 3)) * 8;  // read-side swizzle

    int cur = 0;
    for (int kt = 0; kt < K / 32; ++kt) {
        if (kt + 1 < K / 32) stage(cur ^ 1, kt + 1);
        const unsigned short* As = Al + cur * 4096;
        const unsigned short* Bhs = Bhl + cur * 4096;
        bf16x8 af[4], bh[4], bl[4];
        #pragma unroll
        for (int i = 0; i < 4; ++i)
            af[i] = *reinterpret_cast<const bf16x8*>(As + (wm * 64 + i * 16 + rr) * 32 + slot8);
        #pragma unroll
        for (int j = 0; j < 4; ++j)
            bh[j] = *reinterpret_cast<const bf16x8*>(Bhs + (wn * 64 + j * 16 + rr) * 32 + slot8);
        if constexpr (DUAL) {
            const unsigned short* Bls = Bll + cur * 4096;
            #pragma unroll
            for (int j = 0; j < 4; ++j)
                bl[j] = *reinterpret_cast<const bf16x8*>(Bls + (wn * 64 + j * 16 + rr) * 32 + slot8);
        }
        #pragma unroll
        for (int i = 0; i < 4; ++i)
            #pragma unroll
            for (int j = 0; j < 4; ++j) {
                acc[i][j] = __builtin_amdgcn_mfma_f32_16x16x32_bf16(af[i], bh[j], acc[i][j], 0, 0, 0);
                if constexpr (DUAL)
                    acl[i][j] = __builtin_amdgcn_mfma_f32_16x16x32_bf16(af[i], bl[j], acl[i][j], 0, 0, 0);
            }
        __syncthreads();
        cur ^= 1;
    }

    // epilogue: C/D layout col=lane&15, row=(lane>>4)*4+r
    const int rg = lane >> 4;
    #pragma unroll
    for (int j = 0; j < 4; ++j) {
        const int col = n0 + wn * 64 + j * 16 + rr;
        const float bv = HAS_BIAS ? bias[col] : 0.f;
        #pragma unroll
        for (int i = 0; i < 4; ++i) {
            const int row0 = m0 + wm * 64 + i * 16 + rg * 4;
            #pragma unroll
            for (int r = 0; r < 4; ++r) {
                float val = acc[i][j][r] + bv;
                if constexpr (DUAL) val += acl[i][j][r];
                const size_t off = (size_t)(row0 + r) * N + col;
                if (OUT_BF16) reinterpret_cast<unsigned short*>(Cout)[off] = f2bf(val);
                else          reinterpret_cast<float*>(Cout)[off] = val;
            }
        }
    }
}

// ---------------- per-token HxH attention, one wave per token, full f32 ----------------
// qp: bf16 [32768][1024], kp: f32 [8192][1024], vp: bf16 [8192][1024].
// LN (gamma,beta,eps=1e-5) on q (x0.125) and k, all f32.
// S = qln*kln^T (16x16), softmax over g, x = P*v (16x64), bf16 scrambled store:
// x_scr[b, h*128+n/16, (n%16)*64+d]
__global__ __launch_bounds__(256) void k_attn(
    const unsigned short* __restrict__ qp,
    const float* __restrict__ kp,
    const unsigned short* __restrict__ vp,
    const float* __restrict__ gamma,
    const float* __restrict__ beta,
    unsigned short* __restrict__ xout)
{
    __shared__ float ks[4][16 * 64];
    __shared__ float vs[4][16 * 64];

    const int w = threadIdx.x >> 6;
    const int lane = threadIdx.x & 63;
    const int token = blockIdx.x * 4 + w;   // grid covers exactly 32768 tokens
    const int b = token >> 11;
    const int n = token & 2047;
    const int kb = b & 3;

    const int h = lane >> 2;    // head / row 0..15
    const int qd = lane & 3;    // quarter of head_dim
    const int d0 = qd * 16;

    const unsigned short* qptr = qp + (size_t)token * 1024 + h * 64 + d0;
    const float*          kptr = kp + (size_t)(kb * 2048 + n) * 1024 + h * 64 + d0;
    const unsigned short* vptr = vp + (size_t)(kb * 2048 + n) * 1024 + h * 64 + d0;

    float gm[16], bt[16];
    #pragma unroll
    for (int t = 0; t < 16; ++t) { gm[t] = gamma[d0 + t]; bt[t] = beta[d0 + t]; }

    // ---- load q (bf16), LN in f32, scale 0.125 -> yq regs ----
    float yq[16];
    {
        const uint4* p = reinterpret_cast<const uint4*>(qptr);
        const uint4 u0 = p[0], u1 = p[1];
        const uint32_t uu[8] = {u0.x, u0.y, u0.z, u0.w, u1.x, u1.y, u1.z, u1.w};
        float x[16]; float s = 0.f, sq = 0.f;
        #pragma unroll
        for (int t = 0; t < 8; ++t) {
            const float a = bf2f((unsigned short)(uu[t] & 0xffffu));
            const float c = bf2f((unsigned short)(uu[t] >> 16));
            x[2 * t] = a; x[2 * t + 1] = c;
            s += a + c; sq += a * a + c * c;
        }
        s  += __shfl_xor(s, 1);  s  += __shfl_xor(s, 2);
        sq += __shfl_xor(sq, 1); sq += __shfl_xor(sq, 2);
        const float mu = s * 0.015625f;
        const float var = sq * 0.015625f - mu * mu;
        const float inv = rsqrtf(var + 1e-5f);
        #pragma unroll
        for (int t = 0; t < 16; ++t)
            yq[t] = ((x[t] - mu) * inv * gm[t] + bt[t]) * 0.125f;
    }

    // ---- load k (f32), LN in f32 -> ks LDS ----
    {
        const float4* p = reinterpret_cast<const float4*>(kptr);
        const float4 f0 = p[0], f1 = p[1], f2 = p[2], f3 = p[3];
        float x[16] = {f0.x, f0.y, f0.z, f0.w, f1.x, f1.y, f1.z, f1.w,
                       f2.x, f2.y, f2.z, f2.w, f3.x, f3.y, f3.z, f3.w};
        float s = 0.f, sq = 0.f;
        #pragma unroll
        for (int t = 0; t < 16; ++t) { s += x[t]; sq += x[t] * x[t]; }
        s  += __shfl_xor(s, 1);  s  += __shfl_xor(s, 2);
        sq += __shfl_xor(sq, 1); sq += __shfl_xor(sq, 2);
        const float mu = s * 0.015625f;
        const float var = sq * 0.015625f - mu * mu;
        const float inv = rsqrtf(var + 1e-5f);
        #pragma unroll
        for (int t = 0; t < 16; ++t)
            ks[w][h * 64 + d0 + t] = (x[t] - mu) * inv * gm[t] + bt[t];
    }

    // ---- load v (bf16) -> vs LDS (f32) ----
    {
        const uint4* p = reinterpret_cast<const uint4*>(vptr);
        const uint4 u0 = p[0], u1 = p[1];
        const uint32_t uu[8] = {u0.x, u0.y, u0.z, u0.w, u1.x, u1.y, u1.z, u1.w};
        #pragma unroll
        for (int t = 0; t < 8; ++t) {
            vs[w][h * 64 + d0 + 2 * t]     = bf2f((unsigned short)(uu[t] & 0xffffu));
            vs[w][h * 64 + d0 + 2 * t + 1] = bf2f((unsigned short)(uu[t] >> 16));
        }
    }
    __syncthreads();

    // ---- S[h][g] = sum_d yq[h][d]*kln[g][d]; partial over this lane's 16 d's,
    //      then butterfly over the 4 qd lanes (bit-identical across the group) ----
    float S[16];
    #pragma unroll
    for (int g = 0; g < 16; ++g) {
        float p = 0.f;
        #pragma unroll
        for (int t = 0; t < 16; ++t) p += yq[t] * ks[w][g * 64 + d0 + t];
        p += __shfl_xor(p, 1);
        p += __shfl_xor(p, 2);
        S[g] = p;
    }

    // ---- softmax over g, replicated per lane (no cross-lane needed) ----
    float m = S[0];
    #pragma unroll
    for (int g = 1; g < 16; ++g) m = fmaxf(m, S[g]);
    float sum = 0.f;
    #pragma unroll
    for (int g = 0; g < 16; ++g) { S[g] = __expf(S[g] - m); sum += S[g]; }
    const float rs = 1.f / sum;
    #pragma unroll
    for (int g = 0; g < 16; ++g) S[g] *= rs;

    // ---- x[h][d] = sum_g P[g]*v[g][d] for this lane's 16 d's ----
    float xo[16] = {};
    #pragma unroll
    for (int g = 0; g < 16; ++g) {
        const float pg = S[g];
        #pragma unroll
        for (int t = 0; t < 16; ++t) xo[t] += pg * vs[w][g * 64 + d0 + t];
    }

    // ---- bf16 scrambled store: row = h*128 + n/16, col = (n%16)*64 + d ----
    const size_t obase = (size_t)b * 2048 * 1024;
    const int row = h * 128 + (n >> 4);
    const int col = (n & 15) * 64 + d0;
    uint32_t pk[8];
    #pragma unroll
    for (int t = 0; t < 8; ++t)
        pk[t] = (uint32_t)f2bf(xo[2 * t]) | ((uint32_t)f2bf(xo[2 * t + 1]) << 16);
    uint4* dst = reinterpret_cast<uint4*>(xout + obase + (size_t)row * 1024 + col);
    uint4 lo; lo.x = pk[0]; lo.y = pk[1]; lo.z = pk[2]; lo.w = pk[3];
    uint4 hi; hi.x = pk[4]; hi.y = pk[5]; hi.z = pk[6]; hi.w = pk[7];
    dst[0] = lo; dst[1] = hi;
}

extern "C" void kernel_launch(void* const* d_in, const int* in_sizes, int n_in,
                              void* d_out, int out_size, void* d_ws, size_t ws_size,
                              hipStream_t stream) {
    const float* q     = (const float*)d_in[0];
    const float* k     = (const float*)d_in[1];
    const float* v     = (const float*)d_in[2];
    const float* Wq    = (const float*)d_in[3];
    const float* Wk    = (const float*)d_in[4];
    const float* Wv    = (const float*)d_in[5];
    const float* Wo    = (const float*)d_in[6];
    const float* bo    = (const float*)d_in[7];
    const float* gamma = (const float*)d_in[8];
    const float* beta  = (const float*)d_in[9];
    float* out = (float*)d_out;

    char* ws = (char*)d_ws;
    const size_t MB = 1024 * 1024;
    // [0,64):    qb (bf16 q input) -> later xsc (bf16 scrambled attn out)
    // [64,128):  qpb (bf16 q-proj out)
    // [128,160): kpf (f32 k-proj out)
    // [160,176): vpb (bf16 v-proj out)
    // [176,192): kbb (bf16 k input) -> later vbb (bf16 v input)
    // [192,194): W hi slot (bf16, reused)
    // [194,196): W lo slot (bf16, reused)
    unsigned short* qb   = (unsigned short*)(ws + 0);
    unsigned short* xsc  = (unsigned short*)(ws + 0);
    unsigned short* qpb  = (unsigned short*)(ws + 64 * MB);
    float*          kpf  = (float*)         (ws + 128 * MB);
    unsigned short* vpb  = (unsigned short*)(ws + 160 * MB);
    unsigned short* kbb  = (unsigned short*)(ws + 176 * MB);
    unsigned short* vbb  = (unsigned short*)(ws + 176 * MB);
    unsigned short* Whi  = (unsigned short*)(ws + 192 * MB);
    unsigned short* Wlo  = (unsigned short*)(ws + 194 * MB);

    // ---- k path: fused dual (hi+lo) GEMM into f32 kpf ----
    k_cvt_hl<<<512, 256, 0, stream>>>(Wk, Whi, Wlo, 262144);
    k_cvt<<<1024, 256, 0, stream>>>(k, kbb, 2097152);
    k_gemm<0, 0, 1><<<512, 256, 0, stream>>>(kbb, Whi, Wlo, kpf, nullptr, 8192);

    // ---- v path: plain bf16 ---- (vbb overwrites kbb region: k-proj done)
    k_cvt<<<512, 256, 0, stream>>>(Wv, Whi, 262144);
    k_cvt<<<1024, 256, 0, stream>>>(v, vbb, 2097152);
    k_gemm<1, 0, 0><<<512, 256, 0, stream>>>(vbb, Whi, nullptr, vpb, nullptr, 8192);

    // ---- q path: plain bf16 ----
    k_cvt<<<512, 256, 0, stream>>>(Wq, Whi, 262144);
    k_cvt<<<2048, 256, 0, stream>>>(q, qb, 8388608);
    k_gemm<1, 0, 0><<<2048, 256, 0, stream>>>(qb, Whi, nullptr, qpb, nullptr, 32768);

    // ---- attention (full f32 middle), writes scrambled bf16 over qb region ----
    k_attn<<<8192, 256, 0, stream>>>(qpb, kpf, vpb, gamma, beta, xsc);

    // ---- out path: fused dual (hi+lo) GEMM, f32 + bias into d_out ----
    k_cvt_hl<<<512, 256, 0, stream>>>(Wo, Whi, Wlo, 262144);
    k_gemm<0, 1, 1><<<2048, 256, 0, stream>>>(xsc, Whi, Wlo, out, bo, 32768);
}

// Round 5
// 469.670 us; speedup vs baseline: 1.3844x; 1.0037x over previous
//
#include <hip/hip_runtime.h>
#include <stdint.h>

typedef short bf16x8 __attribute__((ext_vector_type(8)));
typedef float f32x4 __attribute__((ext_vector_type(4)));

#define DEVINL static __device__ __forceinline__

DEVINL unsigned short f2bf(float f) {
    union { float f; uint32_t u; } v; v.f = f;
    return (unsigned short)((v.u + 0x7FFFu + ((v.u >> 16) & 1u)) >> 16);
}
DEVINL float bf2f(unsigned short b) {
    union { uint32_t u; float f; } v; v.u = ((uint32_t)b) << 16;
    return v.f;
}

DEVINL void load_lds16(const void* g, void* l) {
    __builtin_amdgcn_global_load_lds(
        (const __attribute__((address_space(1))) void*)g,
        (__attribute__((address_space(3))) void*)l, 16, 0, 0);
}

// pack 8 f32 -> bf16x8 (RNE)
DEVINL bf16x8 cvt8(f32x4 lo, f32x4 hi) {
    bf16x8 r;
    r[0] = (short)f2bf(lo[0]); r[1] = (short)f2bf(lo[1]);
    r[2] = (short)f2bf(lo[2]); r[3] = (short)f2bf(lo[3]);
    r[4] = (short)f2bf(hi[0]); r[5] = (short)f2bf(hi[1]);
    r[6] = (short)f2bf(hi[2]); r[7] = (short)f2bf(hi[3]);
    return r;
}

// ---------------- f32 -> bf16 convert (weights only) ----------------
__global__ __launch_bounds__(256) void k_cvt(const float* __restrict__ src,
                                             unsigned short* __restrict__ dst, int n4) {
    int stride = gridDim.x * blockDim.x;
    for (int i = blockIdx.x * blockDim.x + threadIdx.x; i < n4; i += stride) {
        float4 f = reinterpret_cast<const float4*>(src)[i];
        ushort4 o;
        o.x = f2bf(f.x); o.y = f2bf(f.y); o.z = f2bf(f.z); o.w = f2bf(f.w);
        reinterpret_cast<ushort4*>(dst)[i] = o;
    }
}

// ---------------- f32 -> bf16 hi/lo split convert ----------------
__global__ __launch_bounds__(256) void k_cvt_hl(const float* __restrict__ src,
                                                unsigned short* __restrict__ hi,
                                                unsigned short* __restrict__ lo, int n4) {
    int stride = gridDim.x * blockDim.x;
    for (int i = blockIdx.x * blockDim.x + threadIdx.x; i < n4; i += stride) {
        float4 f = reinterpret_cast<const float4*>(src)[i];
        ushort4 h, l;
        h.x = f2bf(f.x); l.x = f2bf(f.x - bf2f(h.x));
        h.y = f2bf(f.y); l.y = f2bf(f.y - bf2f(h.y));
        h.z = f2bf(f.z); l.z = f2bf(f.z - bf2f(h.z));
        h.w = f2bf(f.w); l.w = f2bf(f.w - bf2f(h.w));
        reinterpret_cast<ushort4*>(hi)[i] = h;
        reinterpret_cast<ushort4*>(lo)[i] = l;
    }
}

// ---------------- NT GEMM: C[M,N] = A * Bh^T (+ A * Bl^T if DUAL) ----------------
// K = N = 1024 fixed. 128x128 tile, 4 waves, 16x16x32 bf16 MFMA.
// A either bf16 [M,K] or raw f32 [M,K] (A_F32: staged as f32, cvt at fragment
// build). global_load_lds width-16 staging, LDS linear + pre-swizzled global
// source + matching read swizzle (conflict-free), double-buffered, XCD swizzle.
template<int A_F32, int OUT_BF16, int HAS_BIAS, int DUAL>
__global__ __launch_bounds__(256) void k_gemm(
    const void* __restrict__ A,
    const unsigned short* __restrict__ Bh,
    const unsigned short* __restrict__ Bl,
    void* __restrict__ Cout,
    const float* __restrict__ bias, int M)
{
    constexpr int K = 1024;
    constexpr int N = 1024;
    constexpr int ASZ = A_F32 ? 32768 : 16384;           // bytes (2 bufs)
    __shared__ __align__(16) char smem[ASZ + (DUAL ? 2 : 1) * 16384];
    float*          AlF = (float*)smem;                   // [2][4096] f32
    unsigned short* Alb = (unsigned short*)smem;          // [2][4096] bf16
    unsigned short* Bhl = (unsigned short*)(smem + ASZ);  // [2][4096]
    unsigned short* Bll = (unsigned short*)(smem + ASZ + 16384);

    // T1: XCD-aware block swizzle (nwg % 8 == 0 always here)
    const int nwg = gridDim.x;
    const int bid = blockIdx.x;
    const int wg = (bid & 7) * (nwg >> 3) + (bid >> 3);
    const int m0 = (wg >> 3) * 128;      // 8 n-tiles per m-panel (N=1024)
    const int n0 = (wg & 7) * 128;

    const int tid = threadIdx.x;
    const int w = tid >> 6;
    const int lane = tid & 63;
    const int wm = w & 1;
    const int wn = w >> 1;

    // bf16 staging indices (64B rows, 4 segs)
    const int srow = lane >> 2;
    const int sseg = lane & 3;
    const int sslot = sseg ^ ((srow >> 1) & 3);
    // f32 staging indices (128B rows, 8 segs)
    const int arow = lane >> 3;
    const int aseg = lane & 7;

    f32x4 acc[4][4] = {};
    f32x4 acl[4][4] = {};

    const size_t a_base = (size_t)m0 * K;
    const size_t b_base = (size_t)n0 * K;
    const float* Af = (const float*)A;
    const unsigned short* Ab = (const unsigned short*)A;

    auto stage = [&](int buf, int kt) {
        const int k0 = kt * 32;
        if constexpr (A_F32) {
            #pragma unroll
            for (int j = 0; j < 4; ++j) {
                const int chunk = w * 4 + j;             // 16 chunks x 8 rows
                const int row = chunk * 8 + arow;
                const int ss = aseg ^ (row & 7);
                load_lds16(Af + a_base + (size_t)row * K + k0 + ss * 4,
                           AlF + buf * 4096 + chunk * 256);
            }
        } else {
            #pragma unroll
            for (int j = 0; j < 2; ++j) {
                const int chunk = w * 2 + j;             // 8 chunks x 16 rows
                const int row = chunk * 16 + srow;
                load_lds16(Ab + a_base + (size_t)row * K + k0 + sslot * 8,
                           Alb + buf * 4096 + chunk * 512);
            }
        }
        #pragma unroll
        for (int j = 0; j < 2; ++j) {
            const int chunk = w * 2 + j;
            const int row = chunk * 16 + srow;
            const size_t goff = (size_t)row * K + k0 + sslot * 8;
            load_lds16(Bh + b_base + goff, Bhl + buf * 4096 + chunk * 512);
            if constexpr (DUAL)
                load_lds16(Bl + b_base + goff, Bll + buf * 4096 + chunk * 512);
        }
    };

    stage(0, 0);
    __syncthreads();

    const int rr = lane & 15;
    const int kq = lane >> 4;
    const int slot8 = (kq ^ ((rr >> 1) & 3)) * 8;        // bf16 read swizzle

    int cur = 0;
    for (int kt = 0; kt < K / 32; ++kt) {
        if (kt + 1 < K / 32) stage(cur ^ 1, kt + 1);
        bf16x8 af[4], bh[4], bl[4];
        if constexpr (A_F32) {
            const float* As = AlF + cur * 4096;
            #pragma unroll
            for (int i = 0; i < 4; ++i) {
                const int row = wm * 64 + i * 16 + rr;
                const int x7 = row & 7;
                const f32x4 lo = *reinterpret_cast<const f32x4*>(
                    As + row * 32 + (((kq * 2)     ^ x7) << 2));
                const f32x4 hi = *reinterpret_cast<const f32x4*>(
                    As + row * 32 + (((kq * 2 + 1) ^ x7) << 2));
                af[i] = cvt8(lo, hi);
            }
        } else {
            const unsigned short* As = Alb + cur * 4096;
            #pragma unroll
            for (int i = 0; i < 4; ++i)
                af[i] = *reinterpret_cast<const bf16x8*>(
                    As + (wm * 64 + i * 16 + rr) * 32 + slot8);
        }
        {
            const unsigned short* Bhs = Bhl + cur * 4096;
            #pragma unroll
            for (int j = 0; j < 4; ++j)
                bh[j] = *reinterpret_cast<const bf16x8*>(
                    Bhs + (wn * 64 + j * 16 + rr) * 32 + slot8);
        }
        if constexpr (DUAL) {
            const unsigned short* Bls = Bll + cur * 4096;
            #pragma unroll
            for (int j = 0; j < 4; ++j)
                bl[j] = *reinterpret_cast<const bf16x8*>(
                    Bls + (wn * 64 + j * 16 + rr) * 32 + slot8);
        }
        #pragma unroll
        for (int i = 0; i < 4; ++i)
            #pragma unroll
            for (int j = 0; j < 4; ++j) {
                acc[i][j] = __builtin_amdgcn_mfma_f32_16x16x32_bf16(af[i], bh[j], acc[i][j], 0, 0, 0);
                if constexpr (DUAL)
                    acl[i][j] = __builtin_amdgcn_mfma_f32_16x16x32_bf16(af[i], bl[j], acl[i][j], 0, 0, 0);
            }
        __syncthreads();
        cur ^= 1;
    }

    // epilogue: C/D layout col=lane&15, row=(lane>>4)*4+r
    const int rg = lane >> 4;
    #pragma unroll
    for (int j = 0; j < 4; ++j) {
        const int col = n0 + wn * 64 + j * 16 + rr;
        const float bv = HAS_BIAS ? bias[col] : 0.f;
        #pragma unroll
        for (int i = 0; i < 4; ++i) {
            const int row0 = m0 + wm * 64 + i * 16 + rg * 4;
            #pragma unroll
            for (int r = 0; r < 4; ++r) {
                float val = acc[i][j][r] + bv;
                if constexpr (DUAL) val += acl[i][j][r];
                const size_t off = (size_t)(row0 + r) * N + col;
                if (OUT_BF16) reinterpret_cast<unsigned short*>(Cout)[off] = f2bf(val);
                else          reinterpret_cast<float*>(Cout)[off] = val;
            }
        }
    }
}

// ---------------- per-token HxH attention, one wave per token, full f32 ----------------
// qp: bf16 [32768][1024], kp: f32 [8192][1024], vp: bf16 [8192][1024].
// LN (gamma,beta,eps=1e-5) on q (x0.125) and k, all f32.
// S = qln*kln^T (16x16), softmax over g, x = P*v (16x64), bf16 scrambled store:
// x_scr[b, h*128+n/16, (n%16)*64+d]
__global__ __launch_bounds__(256) void k_attn(
    const unsigned short* __restrict__ qp,
    const float* __restrict__ kp,
    const unsigned short* __restrict__ vp,
    const float* __restrict__ gamma,
    const float* __restrict__ beta,
    unsigned short* __restrict__ xout)
{
    __shared__ float ks[4][16 * 64];
    __shared__ float vs[4][16 * 64];

    const int w = threadIdx.x >> 6;
    const int lane = threadIdx.x & 63;
    const int token = blockIdx.x * 4 + w;   // grid covers exactly 32768 tokens
    const int b = token >> 11;
    const int n = token & 2047;
    const int kb = b & 3;

    const int h = lane >> 2;    // head / row 0..15
    const int qd = lane & 3;    // quarter of head_dim
    const int d0 = qd * 16;

    const unsigned short* qptr = qp + (size_t)token * 1024 + h * 64 + d0;
    const float*          kptr = kp + (size_t)(kb * 2048 + n) * 1024 + h * 64 + d0;
    const unsigned short* vptr = vp + (size_t)(kb * 2048 + n) * 1024 + h * 64 + d0;

    float gm[16], bt[16];
    #pragma unroll
    for (int t = 0; t < 16; ++t) { gm[t] = gamma[d0 + t]; bt[t] = beta[d0 + t]; }

    // ---- load q (bf16), LN in f32, scale 0.125 -> yq regs ----
    float yq[16];
    {
        const uint4* p = reinterpret_cast<const uint4*>(qptr);
        const uint4 u0 = p[0], u1 = p[1];
        const uint32_t uu[8] = {u0.x, u0.y, u0.z, u0.w, u1.x, u1.y, u1.z, u1.w};
        float x[16]; float s = 0.f, sq = 0.f;
        #pragma unroll
        for (int t = 0; t < 8; ++t) {
            const float a = bf2f((unsigned short)(uu[t] & 0xffffu));
            const float c = bf2f((unsigned short)(uu[t] >> 16));
            x[2 * t] = a; x[2 * t + 1] = c;
            s += a + c; sq += a * a + c * c;
        }
        s  += __shfl_xor(s, 1);  s  += __shfl_xor(s, 2);
        sq += __shfl_xor(sq, 1); sq += __shfl_xor(sq, 2);
        const float mu = s * 0.015625f;
        const float var = sq * 0.015625f - mu * mu;
        const float inv = rsqrtf(var + 1e-5f);
        #pragma unroll
        for (int t = 0; t < 16; ++t)
            yq[t] = ((x[t] - mu) * inv * gm[t] + bt[t]) * 0.125f;
    }

    // ---- load k (f32), LN in f32 -> ks LDS ----
    {
        const float4* p = reinterpret_cast<const float4*>(kptr);
        const float4 f0 = p[0], f1 = p[1], f2 = p[2], f3 = p[3];
        float x[16] = {f0.x, f0.y, f0.z, f0.w, f1.x, f1.y, f1.z, f1.w,
                       f2.x, f2.y, f2.z, f2.w, f3.x, f3.y, f3.z, f3.w};
        float s = 0.f, sq = 0.f;
        #pragma unroll
        for (int t = 0; t < 16; ++t) { s += x[t]; sq += x[t] * x[t]; }
        s  += __shfl_xor(s, 1);  s  += __shfl_xor(s, 2);
        sq += __shfl_xor(sq, 1); sq += __shfl_xor(sq, 2);
        const float mu = s * 0.015625f;
        const float var = sq * 0.015625f - mu * mu;
        const float inv = rsqrtf(var + 1e-5f);
        #pragma unroll
        for (int t = 0; t < 16; ++t)
            ks[w][h * 64 + d0 + t] = (x[t] - mu) * inv * gm[t] + bt[t];
    }

    // ---- load v (bf16) -> vs LDS (f32) ----
    {
        const uint4* p = reinterpret_cast<const uint4*>(vptr);
        const uint4 u0 = p[0], u1 = p[1];
        const uint32_t uu[8] = {u0.x, u0.y, u0.z, u0.w, u1.x, u1.y, u1.z, u1.w};
        #pragma unroll
        for (int t = 0; t < 8; ++t) {
            vs[w][h * 64 + d0 + 2 * t]     = bf2f((unsigned short)(uu[t] & 0xffffu));
            vs[w][h * 64 + d0 + 2 * t + 1] = bf2f((unsigned short)(uu[t] >> 16));
        }
    }
    __syncthreads();

    // ---- S[h][g] = sum_d yq[h][d]*kln[g][d]; partial over this lane's 16 d's,
    //      then butterfly over the 4 qd lanes (bit-identical across the group) ----
    float S[16];
    #pragma unroll
    for (int g = 0; g < 16; ++g) {
        float p = 0.f;
        #pragma unroll
        for (int t = 0; t < 16; ++t) p += yq[t] * ks[w][g * 64 + d0 + t];
        p += __shfl_xor(p, 1);
        p += __shfl_xor(p, 2);
        S[g] = p;
    }

    // ---- softmax over g, replicated per lane (no cross-lane needed) ----
    float m = S[0];
    #pragma unroll
    for (int g = 1; g < 16; ++g) m = fmaxf(m, S[g]);
    float sum = 0.f;
    #pragma unroll
    for (int g = 0; g < 16; ++g) { S[g] = __expf(S[g] - m); sum += S[g]; }
    const float rs = 1.f / sum;
    #pragma unroll
    for (int g = 0; g < 16; ++g) S[g] *= rs;

    // ---- x[h][d] = sum_g P[g]*v[g][d] for this lane's 16 d's ----
    float xo[16] = {};
    #pragma unroll
    for (int g = 0; g < 16; ++g) {
        const float pg = S[g];
        #pragma unroll
        for (int t = 0; t < 16; ++t) xo[t] += pg * vs[w][g * 64 + d0 + t];
    }

    // ---- bf16 scrambled store: row = h*128 + n/16, col = (n%16)*64 + d ----
    const size_t obase = (size_t)b * 2048 * 1024;
    const int row = h * 128 + (n >> 4);
    const int col = (n & 15) * 64 + d0;
    uint32_t pk[8];
    #pragma unroll
    for (int t = 0; t < 8; ++t)
        pk[t] = (uint32_t)f2bf(xo[2 * t]) | ((uint32_t)f2bf(xo[2 * t + 1]) << 16);
    uint4* dst = reinterpret_cast<uint4*>(xout + obase + (size_t)row * 1024 + col);
    uint4 lo; lo.x = pk[0]; lo.y = pk[1]; lo.z = pk[2]; lo.w = pk[3];
    uint4 hi; hi.x = pk[4]; hi.y = pk[5]; hi.z = pk[6]; hi.w = pk[7];
    dst[0] = lo; dst[1] = hi;
}

extern "C" void kernel_launch(void* const* d_in, const int* in_sizes, int n_in,
                              void* d_out, int out_size, void* d_ws, size_t ws_size,
                              hipStream_t stream) {
    const float* q     = (const float*)d_in[0];
    const float* k     = (const float*)d_in[1];
    const float* v     = (const float*)d_in[2];
    const float* Wq    = (const float*)d_in[3];
    const float* Wk    = (const float*)d_in[4];
    const float* Wv    = (const float*)d_in[5];
    const float* Wo    = (const float*)d_in[6];
    const float* bo    = (const float*)d_in[7];
    const float* gamma = (const float*)d_in[8];
    const float* beta  = (const float*)d_in[9];
    float* out = (float*)d_out;

    char* ws = (char*)d_ws;
    const size_t MB = 1024 * 1024;
    // [0,64):    xsc (bf16 scrambled attn out)
    // [64,128):  qpb (bf16 q-proj out)
    // [128,160): kpf (f32 k-proj out)
    // [160,176): vpb (bf16 v-proj out)
    // [176..):   weight slots, 2 MiB each
    unsigned short* xsc = (unsigned short*)(ws + 0);
    unsigned short* qpb = (unsigned short*)(ws + 64 * MB);
    float*          kpf = (float*)         (ws + 128 * MB);
    unsigned short* vpb = (unsigned short*)(ws + 160 * MB);
    unsigned short* Wkh = (unsigned short*)(ws + 176 * MB);
    unsigned short* Wkl = (unsigned short*)(ws + 178 * MB);
    unsigned short* Wvb = (unsigned short*)(ws + 180 * MB);
    unsigned short* Wqb = (unsigned short*)(ws + 182 * MB);
    unsigned short* Wob = (unsigned short*)(ws + 184 * MB);

    // weight converts (tiny)
    k_cvt_hl<<<512, 256, 0, stream>>>(Wk, Wkh, Wkl, 262144);
    k_cvt<<<512, 256, 0, stream>>>(Wv, Wvb, 262144);
    k_cvt<<<512, 256, 0, stream>>>(Wq, Wqb, 262144);
    k_cvt<<<512, 256, 0, stream>>>(Wo, Wob, 262144);

    // projections: A read directly as f32 (fused convert)
    k_gemm<1, 0, 0, 1><<<512, 256, 0, stream>>>(k, Wkh, Wkl, kpf, nullptr, 8192);
    k_gemm<1, 1, 0, 0><<<512, 256, 0, stream>>>(v, Wvb, nullptr, vpb, nullptr, 8192);
    k_gemm<1, 1, 0, 0><<<2048, 256, 0, stream>>>(q, Wqb, nullptr, qpb, nullptr, 32768);

    // per-token attention (full f32 middle), scrambled bf16 out
    k_attn<<<8192, 256, 0, stream>>>(qpb, kpf, vpb, gamma, beta, xsc);

    // output projection: single bf16 Wo, f32 + bias into d_out
    k_gemm<0, 0, 1, 0><<<2048, 256, 0, stream>>>(xsc, Wob, nullptr, out, bo, 32768);
}

// Round 6
// 381.166 us; speedup vs baseline: 1.7059x; 1.2322x over previous
//
#include <hip/hip_runtime.h>
#include <stdint.h>

typedef short bf16x8 __attribute__((ext_vector_type(8)));
typedef float f32x4 __attribute__((ext_vector_type(4)));

#define DEVINL static __device__ __forceinline__

DEVINL unsigned short f2bf(float f) {
    union { float f; uint32_t u; } v; v.f = f;
    return (unsigned short)((v.u + 0x7FFFu + ((v.u >> 16) & 1u)) >> 16);
}
DEVINL float bf2f(unsigned short b) {
    union { uint32_t u; float f; } v; v.u = ((uint32_t)b) << 16;
    return v.f;
}

DEVINL void load_lds16(const void* g, void* l) {
    __builtin_amdgcn_global_load_lds(
        (const __attribute__((address_space(1))) void*)g,
        (__attribute__((address_space(3))) void*)l, 16, 0, 0);
}

// ---------------- f32 -> bf16 convert ----------------
__global__ __launch_bounds__(256) void k_cvt(const float* __restrict__ src,
                                             unsigned short* __restrict__ dst, int n4) {
    int stride = gridDim.x * blockDim.x;
    for (int i = blockIdx.x * blockDim.x + threadIdx.x; i < n4; i += stride) {
        float4 f = reinterpret_cast<const float4*>(src)[i];
        ushort4 o;
        o.x = f2bf(f.x); o.y = f2bf(f.y); o.z = f2bf(f.z); o.w = f2bf(f.w);
        reinterpret_cast<ushort4*>(dst)[i] = o;
    }
}

// ---------------- f32 -> bf16 hi/lo split convert ----------------
__global__ __launch_bounds__(256) void k_cvt_hl(const float* __restrict__ src,
                                                unsigned short* __restrict__ hi,
                                                unsigned short* __restrict__ lo, int n4) {
    int stride = gridDim.x * blockDim.x;
    for (int i = blockIdx.x * blockDim.x + threadIdx.x; i < n4; i += stride) {
        float4 f = reinterpret_cast<const float4*>(src)[i];
        ushort4 h, l;
        h.x = f2bf(f.x); l.x = f2bf(f.x - bf2f(h.x));
        h.y = f2bf(f.y); l.y = f2bf(f.y - bf2f(h.y));
        h.z = f2bf(f.z); l.z = f2bf(f.z - bf2f(h.z));
        h.w = f2bf(f.w); l.w = f2bf(f.w - bf2f(h.w));
        reinterpret_cast<ushort4*>(hi)[i] = h;
        reinterpret_cast<ushort4*>(lo)[i] = l;
    }
}

// ---------------- 128x128 NT GEMM (round-3 proven, bf16 A) ----------------
// C[M,N] = A * Bh^T (+ A * Bl^T if DUAL). K = N = 1024.
template<int OUT_BF16, int HAS_BIAS, int DUAL>
__global__ __launch_bounds__(256) void k_gemm(
    const unsigned short* __restrict__ A,
    const unsigned short* __restrict__ Bh,
    const unsigned short* __restrict__ Bl,
    void* __restrict__ Cout,
    const float* __restrict__ bias, int M)
{
    constexpr int K = 1024;
    constexpr int N = 1024;
    __shared__ __align__(16) unsigned short smem[(DUAL ? 6 : 4) * 4096];
    unsigned short* Al  = smem;
    unsigned short* Bhl = smem + 2 * 4096;
    unsigned short* Bll = DUAL ? smem + 4 * 4096 : nullptr;

    const int nwg = gridDim.x;
    const int bid = blockIdx.x;
    const int wg = (bid & 7) * (nwg >> 3) + (bid >> 3);
    const int m0 = (wg >> 3) * 128;
    const int n0 = (wg & 7) * 128;

    const int tid = threadIdx.x;
    const int w = tid >> 6;
    const int lane = tid & 63;
    const int wm = w & 1;
    const int wn = w >> 1;

    const int srow = lane >> 2;
    const int sseg = lane & 3;
    const int sslot = sseg ^ ((srow >> 1) & 3);

    f32x4 acc[4][4] = {};
    f32x4 acl[4][4] = {};

    const size_t a_base = (size_t)m0 * K;
    const size_t b_base = (size_t)n0 * K;

    auto stage = [&](int buf, int kt) {
        const int k0 = kt * 32;
        #pragma unroll
        for (int j = 0; j < 2; ++j) {
            const int chunk = w * 2 + j;
            const int row = chunk * 16 + srow;
            const size_t goff = (size_t)row * K + k0 + sslot * 8;
            load_lds16(A + a_base + goff, Al + buf * 4096 + chunk * 512);
            load_lds16(Bh + b_base + goff, Bhl + buf * 4096 + chunk * 512);
            if (DUAL) load_lds16(Bl + b_base + goff, Bll + buf * 4096 + chunk * 512);
        }
    };

    stage(0, 0);
    __syncthreads();

    const int rr = lane & 15;
    const int slot8 = ((lane >> 4) ^ ((rr >> 1) & 3)) * 8;

    int cur = 0;
    for (int kt = 0; kt < K / 32; ++kt) {
        if (kt + 1 < K / 32) stage(cur ^ 1, kt + 1);
        const unsigned short* As = Al + cur * 4096;
        const unsigned short* Bhs = Bhl + cur * 4096;
        bf16x8 af[4], bh[4], bl[4];
        #pragma unroll
        for (int i = 0; i < 4; ++i)
            af[i] = *reinterpret_cast<const bf16x8*>(
                As + (wm * 64 + i * 16 + rr) * 32 + slot8);
        #pragma unroll
        for (int j = 0; j < 4; ++j)
            bh[j] = *reinterpret_cast<const bf16x8*>(
                Bhs + (wn * 64 + j * 16 + rr) * 32 + slot8);
        if constexpr (DUAL) {
            const unsigned short* Bls = Bll + cur * 4096;
            #pragma unroll
            for (int j = 0; j < 4; ++j)
                bl[j] = *reinterpret_cast<const bf16x8*>(
                    Bls + (wn * 64 + j * 16 + rr) * 32 + slot8);
        }
        #pragma unroll
        for (int i = 0; i < 4; ++i)
            #pragma unroll
            for (int j = 0; j < 4; ++j) {
                acc[i][j] = __builtin_amdgcn_mfma_f32_16x16x32_bf16(af[i], bh[j], acc[i][j], 0, 0, 0);
                if constexpr (DUAL)
                    acl[i][j] = __builtin_amdgcn_mfma_f32_16x16x32_bf16(af[i], bl[j], acl[i][j], 0, 0, 0);
            }
        __syncthreads();
        cur ^= 1;
    }

    const int rg = lane >> 4;
    #pragma unroll
    for (int j = 0; j < 4; ++j) {
        const int col = n0 + wn * 64 + j * 16 + rr;
        const float bv = HAS_BIAS ? bias[col] : 0.f;
        #pragma unroll
        for (int i = 0; i < 4; ++i) {
            const int row0 = m0 + wm * 64 + i * 16 + rg * 4;
            #pragma unroll
            for (int r = 0; r < 4; ++r) {
                float val = acc[i][j][r] + bv;
                if constexpr (DUAL) val += acl[i][j][r];
                const size_t off = (size_t)(row0 + r) * N + col;
                if (OUT_BF16) reinterpret_cast<unsigned short*>(Cout)[off] = f2bf(val);
                else          reinterpret_cast<float*>(Cout)[off] = val;
            }
        }
    }
}

// ---------------- 256x256 NT GEMM, 8 waves, BK=64, phase-interleaved ----------------
// LDS [buf][A/B][ksub][256 rows][32 cols]: 64B rows, proven conflict-free swizzle.
// One vmcnt(0)+barrier per K-tile; all prefetch loads issued right after barrier.
template<int OUT_BF16, int HAS_BIAS>
__global__ __launch_bounds__(512, 2) void k_gemm256(
    const unsigned short* __restrict__ A,
    const unsigned short* __restrict__ B,
    void* __restrict__ Cout,
    const float* __restrict__ bias)
{
    constexpr int K = 1024;
    constexpr int N = 1024;
    __shared__ __align__(16) unsigned short lds[2][2][2][256][32];  // 128 KiB

    const int nwg = gridDim.x;            // 512 (M=32768)
    const int bid = blockIdx.x;
    const int wg  = (bid & 7) * (nwg >> 3) + (bid >> 3);   // XCD swizzle
    const int m0 = (wg >> 2) * 256;
    const int n0 = (wg & 3) * 256;

    const int tid = threadIdx.x;
    const int w = tid >> 6;               // 0..7
    const int lane = tid & 63;
    const int wr = w >> 2;                // M half (0..1)
    const int wc = w & 3;                 // N quarter (0..3)

    const int srow = lane >> 2;           // 0..15
    const int sseg = lane & 3;
    const int sslot = sseg ^ ((srow >> 1) & 3);

    f32x4 acc[8][4] = {};

    auto stage = [&](int buf, int kt) {
        const int k0 = kt * 64;
        #pragma unroll
        for (int j = 0; j < 8; ++j) {
            const int ch = w * 8 + j;             // 0..63
            const int ab = ch >> 5;               // 0:A 1:B
            const int ks = (ch >> 4) & 1;         // ksub
            const int rg = ch & 15;               // 16-row group
            const int row = rg * 16 + srow;
            const unsigned short* src =
                (ab ? B + (size_t)(n0 + row) * K : A + (size_t)(m0 + row) * K)
                + k0 + ks * 32 + sslot * 8;
            load_lds16(src, &lds[buf][ab][ks][rg * 16][0]);
        }
    };

    const int rr = lane & 15;
    const int rdslot = ((lane >> 4) ^ ((rr >> 1) & 3)) * 8;

    stage(0, 0);

    int cur = 0;
    for (int kt = 0; kt < K / 64; ++kt) {
        __syncthreads();                  // emits vmcnt(0)+lgkmcnt(0): tile-t loads landed
        if (kt + 1 < K / 64) stage(cur ^ 1, kt + 1);   // issue-early, max latency cover

        bf16x8 a[4][2], b[2][2];
        #pragma unroll
        for (int ph = 0; ph < 4; ++ph) {
            const int mh = (ph >> 1) & 1;               // 0,0,1,1
            const int nh = (ph == 1 || ph == 2) ? 1 : 0;
            if (ph == 0 || ph == 2) {
                #pragma unroll
                for (int i = 0; i < 4; ++i)
                    #pragma unroll
                    for (int ks = 0; ks < 2; ++ks)
                        a[i][ks] = *reinterpret_cast<const bf16x8*>(
                            &lds[cur][0][ks][wr * 128 + (mh * 4 + i) * 16 + rr][0] + rdslot);
            }
            #pragma unroll
            for (int j = 0; j < 2; ++j)
                #pragma unroll
                for (int ks = 0; ks < 2; ++ks)
                    b[j][ks] = *reinterpret_cast<const bf16x8*>(
                        &lds[cur][1][ks][wc * 64 + (nh * 2 + j) * 16 + rr][0] + rdslot);
            __builtin_amdgcn_s_setprio(1);
            #pragma unroll
            for (int i = 0; i < 4; ++i)
                #pragma unroll
                for (int j = 0; j < 2; ++j)
                    #pragma unroll
                    for (int ks = 0; ks < 2; ++ks)
                        acc[mh * 4 + i][nh * 2 + j] = __builtin_amdgcn_mfma_f32_16x16x32_bf16(
                            a[i][ks], b[j][ks], acc[mh * 4 + i][nh * 2 + j], 0, 0, 0);
            __builtin_amdgcn_s_setprio(0);
        }
        cur ^= 1;
    }

    const int rg = lane >> 4;
    #pragma unroll
    for (int jj = 0; jj < 4; ++jj) {
        const int col = n0 + wc * 64 + jj * 16 + rr;
        const float bv = HAS_BIAS ? bias[col] : 0.f;
        #pragma unroll
        for (int i = 0; i < 8; ++i) {
            const int row0 = m0 + wr * 128 + i * 16 + rg * 4;
            #pragma unroll
            for (int r = 0; r < 4; ++r) {
                const float val = acc[i][jj][r] + bv;
                const size_t off = (size_t)(row0 + r) * N + col;
                if (OUT_BF16) reinterpret_cast<unsigned short*>(Cout)[off] = f2bf(val);
                else          reinterpret_cast<float*>(Cout)[off] = val;
            }
        }
    }
}

// ---------------- per-token HxH attention, one wave per token, full f32 ----------------
__global__ __launch_bounds__(256) void k_attn(
    const unsigned short* __restrict__ qp,
    const float* __restrict__ kp,
    const unsigned short* __restrict__ vp,
    const float* __restrict__ gamma,
    const float* __restrict__ beta,
    unsigned short* __restrict__ xout)
{
    __shared__ float ks[4][16 * 64];
    __shared__ float vs[4][16 * 64];

    const int w = threadIdx.x >> 6;
    const int lane = threadIdx.x & 63;
    const int token = blockIdx.x * 4 + w;
    const int b = token >> 11;
    const int n = token & 2047;
    const int kb = b & 3;

    const int h = lane >> 2;
    const int qd = lane & 3;
    const int d0 = qd * 16;

    const unsigned short* qptr = qp + (size_t)token * 1024 + h * 64 + d0;
    const float*          kptr = kp + (size_t)(kb * 2048 + n) * 1024 + h * 64 + d0;
    const unsigned short* vptr = vp + (size_t)(kb * 2048 + n) * 1024 + h * 64 + d0;

    float gm[16], bt[16];
    #pragma unroll
    for (int t = 0; t < 16; ++t) { gm[t] = gamma[d0 + t]; bt[t] = beta[d0 + t]; }

    float yq[16];
    {
        const uint4* p = reinterpret_cast<const uint4*>(qptr);
        const uint4 u0 = p[0], u1 = p[1];
        const uint32_t uu[8] = {u0.x, u0.y, u0.z, u0.w, u1.x, u1.y, u1.z, u1.w};
        float x[16]; float s = 0.f, sq = 0.f;
        #pragma unroll
        for (int t = 0; t < 8; ++t) {
            const float a = bf2f((unsigned short)(uu[t] & 0xffffu));
            const float c = bf2f((unsigned short)(uu[t] >> 16));
            x[2 * t] = a; x[2 * t + 1] = c;
            s += a + c; sq += a * a + c * c;
        }
        s  += __shfl_xor(s, 1);  s  += __shfl_xor(s, 2);
        sq += __shfl_xor(sq, 1); sq += __shfl_xor(sq, 2);
        const float mu = s * 0.015625f;
        const float var = sq * 0.015625f - mu * mu;
        const float inv = rsqrtf(var + 1e-5f);
        #pragma unroll
        for (int t = 0; t < 16; ++t)
            yq[t] = ((x[t] - mu) * inv * gm[t] + bt[t]) * 0.125f;
    }

    {
        const float4* p = reinterpret_cast<const float4*>(kptr);
        const float4 f0 = p[0], f1 = p[1], f2 = p[2], f3 = p[3];
        float x[16] = {f0.x, f0.y, f0.z, f0.w, f1.x, f1.y, f1.z, f1.w,
                       f2.x, f2.y, f2.z, f2.w, f3.x, f3.y, f3.z, f3.w};
        float s = 0.f, sq = 0.f;
        #pragma unroll
        for (int t = 0; t < 16; ++t) { s += x[t]; sq += x[t] * x[t]; }
        s  += __shfl_xor(s, 1);  s  += __shfl_xor(s, 2);
        sq += __shfl_xor(sq, 1); sq += __shfl_xor(sq, 2);
        const float mu = s * 0.015625f;
        const float var = sq * 0.015625f - mu * mu;
        const float inv = rsqrtf(var + 1e-5f);
        #pragma unroll
        for (int t = 0; t < 16; ++t)
            ks[w][h * 64 + d0 + t] = (x[t] - mu) * inv * gm[t] + bt[t];
    }

    {
        const uint4* p = reinterpret_cast<const uint4*>(vptr);
        const uint4 u0 = p[0], u1 = p[1];
        const uint32_t uu[8] = {u0.x, u0.y, u0.z, u0.w, u1.x, u1.y, u1.z, u1.w};
        #pragma unroll
        for (int t = 0; t < 8; ++t) {
            vs[w][h * 64 + d0 + 2 * t]     = bf2f((unsigned short)(uu[t] & 0xffffu));
            vs[w][h * 64 + d0 + 2 * t + 1] = bf2f((unsigned short)(uu[t] >> 16));
        }
    }
    __syncthreads();

    float S[16];
    #pragma unroll
    for (int g = 0; g < 16; ++g) {
        float p = 0.f;
        #pragma unroll
        for (int t = 0; t < 16; ++t) p += yq[t] * ks[w][g * 64 + d0 + t];
        p += __shfl_xor(p, 1);
        p += __shfl_xor(p, 2);
        S[g] = p;
    }

    float m = S[0];
    #pragma unroll
    for (int g = 1; g < 16; ++g) m = fmaxf(m, S[g]);
    float sum = 0.f;
    #pragma unroll
    for (int g = 0; g < 16; ++g) { S[g] = __expf(S[g] - m); sum += S[g]; }
    const float rs = 1.f / sum;
    #pragma unroll
    for (int g = 0; g < 16; ++g) S[g] *= rs;

    float xo[16] = {};
    #pragma unroll
    for (int g = 0; g < 16; ++g) {
        const float pg = S[g];
        #pragma unroll
        for (int t = 0; t < 16; ++t) xo[t] += pg * vs[w][g * 64 + d0 + t];
    }

    const size_t obase = (size_t)b * 2048 * 1024;
    const int row = h * 128 + (n >> 4);
    const int col = (n & 15) * 64 + d0;
    uint32_t pk[8];
    #pragma unroll
    for (int t = 0; t < 8; ++t)
        pk[t] = (uint32_t)f2bf(xo[2 * t]) | ((uint32_t)f2bf(xo[2 * t + 1]) << 16);
    uint4* dst = reinterpret_cast<uint4*>(xout + obase + (size_t)row * 1024 + col);
    uint4 lo; lo.x = pk[0]; lo.y = pk[1]; lo.z = pk[2]; lo.w = pk[3];
    uint4 hi; hi.x = pk[4]; hi.y = pk[5]; hi.z = pk[6]; hi.w = pk[7];
    dst[0] = lo; dst[1] = hi;
}

extern "C" void kernel_launch(void* const* d_in, const int* in_sizes, int n_in,
                              void* d_out, int out_size, void* d_ws, size_t ws_size,
                              hipStream_t stream) {
    const float* q     = (const float*)d_in[0];
    const float* k     = (const float*)d_in[1];
    const float* v     = (const float*)d_in[2];
    const float* Wq    = (const float*)d_in[3];
    const float* Wk    = (const float*)d_in[4];
    const float* Wv    = (const float*)d_in[5];
    const float* Wo    = (const float*)d_in[6];
    const float* bo    = (const float*)d_in[7];
    const float* gamma = (const float*)d_in[8];
    const float* beta  = (const float*)d_in[9];
    float* out = (float*)d_out;

    char* ws = (char*)d_ws;
    const size_t MB = 1024 * 1024;
    // [0,64):    qb (bf16 q input) -> later xsc (bf16 scrambled attn out)
    // [64,128):  qpb | [128,160): kpf f32 | [160,176): vpb
    // [176,192): kbb -> vbb | [192..): weight slots
    unsigned short* qb  = (unsigned short*)(ws + 0);
    unsigned short* xsc = (unsigned short*)(ws + 0);
    unsigned short* qpb = (unsigned short*)(ws + 64 * MB);
    float*          kpf = (float*)         (ws + 128 * MB);
    unsigned short* vpb = (unsigned short*)(ws + 160 * MB);
    unsigned short* kbb = (unsigned short*)(ws + 176 * MB);
    unsigned short* vbb = (unsigned short*)(ws + 176 * MB);
    unsigned short* Wkh = (unsigned short*)(ws + 192 * MB);
    unsigned short* Wkl = (unsigned short*)(ws + 194 * MB);
    unsigned short* Wvb = (unsigned short*)(ws + 196 * MB);
    unsigned short* Wqb = (unsigned short*)(ws + 198 * MB);
    unsigned short* Wob = (unsigned short*)(ws + 200 * MB);

    // ---- k path: dual (hi+lo) 128^2 GEMM into f32 kpf ----
    k_cvt_hl<<<512, 256, 0, stream>>>(Wk, Wkh, Wkl, 262144);
    k_cvt<<<1024, 256, 0, stream>>>(k, kbb, 2097152);
    k_gemm<0, 0, 1><<<512, 256, 0, stream>>>(kbb, Wkh, Wkl, kpf, nullptr, 8192);

    // ---- v path (vbb overwrites kbb after k-proj done) ----
    k_cvt<<<512, 256, 0, stream>>>(Wv, Wvb, 262144);
    k_cvt<<<1024, 256, 0, stream>>>(v, vbb, 2097152);
    k_gemm<1, 0, 0><<<512, 256, 0, stream>>>(vbb, Wvb, nullptr, vpb, nullptr, 8192);

    // ---- q path: 256^2 phase-interleaved GEMM ----
    k_cvt<<<512, 256, 0, stream>>>(Wq, Wqb, 262144);
    k_cvt<<<2048, 256, 0, stream>>>(q, qb, 8388608);
    k_gemm256<1, 0><<<512, 512, 0, stream>>>(qb, Wqb, qpb, nullptr);

    // ---- attention (full f32 middle), scrambled bf16 out over qb ----
    k_attn<<<8192, 256, 0, stream>>>(qpb, kpf, vpb, gamma, beta, xsc);

    // ---- out path: 256^2 GEMM, f32 + bias into d_out ----
    k_cvt<<<512, 256, 0, stream>>>(Wo, Wob, 262144);
    k_gemm256<0, 1><<<512, 512, 0, stream>>>(xsc, Wob, out, bo);
}

// Round 8
// 375.945 us; speedup vs baseline: 1.7296x; 1.0139x over previous
//
#include <hip/hip_runtime.h>
#include <stdint.h>

typedef short bf16x8 __attribute__((ext_vector_type(8)));
typedef float f32x4 __attribute__((ext_vector_type(4)));

#define DEVINL static __device__ __forceinline__

DEVINL unsigned short f2bf(float f) {
    union { float f; uint32_t u; } v; v.f = f;
    return (unsigned short)((v.u + 0x7FFFu + ((v.u >> 16) & 1u)) >> 16);
}
DEVINL float bf2f(unsigned short b) {
    union { uint32_t u; float f; } v; v.u = ((uint32_t)b) << 16;
    return v.f;
}

DEVINL void load_lds16(const void* g, void* l) {
    __builtin_amdgcn_global_load_lds(
        (const __attribute__((address_space(1))) void*)g,
        (__attribute__((address_space(3))) void*)l, 16, 0, 0);
}

// ---------------- f32 -> bf16 convert ----------------
__global__ __launch_bounds__(256) void k_cvt(const float* __restrict__ src,
                                             unsigned short* __restrict__ dst, int n4) {
    int stride = gridDim.x * blockDim.x;
    for (int i = blockIdx.x * blockDim.x + threadIdx.x; i < n4; i += stride) {
        float4 f = reinterpret_cast<const float4*>(src)[i];
        ushort4 o;
        o.x = f2bf(f.x); o.y = f2bf(f.y); o.z = f2bf(f.z); o.w = f2bf(f.w);
        reinterpret_cast<ushort4*>(dst)[i] = o;
    }
}

// ---------------- f32 -> bf16 hi/lo split convert ----------------
__global__ __launch_bounds__(256) void k_cvt_hl(const float* __restrict__ src,
                                                unsigned short* __restrict__ hi,
                                                unsigned short* __restrict__ lo, int n4) {
    int stride = gridDim.x * blockDim.x;
    for (int i = blockIdx.x * blockDim.x + threadIdx.x; i < n4; i += stride) {
        float4 f = reinterpret_cast<const float4*>(src)[i];
        ushort4 h, l;
        h.x = f2bf(f.x); l.x = f2bf(f.x - bf2f(h.x));
        h.y = f2bf(f.y); l.y = f2bf(f.y - bf2f(h.y));
        h.z = f2bf(f.z); l.z = f2bf(f.z - bf2f(h.z));
        h.w = f2bf(f.w); l.w = f2bf(f.w - bf2f(h.w));
        reinterpret_cast<ushort4*>(hi)[i] = h;
        reinterpret_cast<ushort4*>(lo)[i] = l;
    }
}

// ---------------- 128x128 NT GEMM (round-3 proven, bf16 A) ----------------
template<int OUT_BF16, int HAS_BIAS, int DUAL>
__global__ __launch_bounds__(256) void k_gemm(
    const unsigned short* __restrict__ A,
    const unsigned short* __restrict__ Bh,
    const unsigned short* __restrict__ Bl,
    void* __restrict__ Cout,
    const float* __restrict__ bias, int M)
{
    constexpr int K = 1024;
    constexpr int N = 1024;
    __shared__ __align__(16) unsigned short smem[(DUAL ? 6 : 4) * 4096];
    unsigned short* Al  = smem;
    unsigned short* Bhl = smem + 2 * 4096;
    unsigned short* Bll = DUAL ? smem + 4 * 4096 : nullptr;

    const int nwg = gridDim.x;
    const int bid = blockIdx.x;
    const int wg = (bid & 7) * (nwg >> 3) + (bid >> 3);
    const int m0 = (wg >> 3) * 128;
    const int n0 = (wg & 7) * 128;

    const int tid = threadIdx.x;
    const int w = tid >> 6;
    const int lane = tid & 63;
    const int wm = w & 1;
    const int wn = w >> 1;

    const int srow = lane >> 2;
    const int sseg = lane & 3;
    const int sslot = sseg ^ ((srow >> 1) & 3);

    f32x4 acc[4][4] = {};
    f32x4 acl[4][4] = {};

    const size_t a_base = (size_t)m0 * K;
    const size_t b_base = (size_t)n0 * K;

    auto stage = [&](int buf, int kt) {
        const int k0 = kt * 32;
        #pragma unroll
        for (int j = 0; j < 2; ++j) {
            const int chunk = w * 2 + j;
            const int row = chunk * 16 + srow;
            const size_t goff = (size_t)row * K + k0 + sslot * 8;
            load_lds16(A + a_base + goff, Al + buf * 4096 + chunk * 512);
            load_lds16(Bh + b_base + goff, Bhl + buf * 4096 + chunk * 512);
            if (DUAL) load_lds16(Bl + b_base + goff, Bll + buf * 4096 + chunk * 512);
        }
    };

    stage(0, 0);
    __syncthreads();

    const int rr = lane & 15;
    const int slot8 = ((lane >> 4) ^ ((rr >> 1) & 3)) * 8;

    int cur = 0;
    for (int kt = 0; kt < K / 32; ++kt) {
        if (kt + 1 < K / 32) stage(cur ^ 1, kt + 1);
        const unsigned short* As = Al + cur * 4096;
        const unsigned short* Bhs = Bhl + cur * 4096;
        bf16x8 af[4], bh[4], bl[4];
        #pragma unroll
        for (int i = 0; i < 4; ++i)
            af[i] = *reinterpret_cast<const bf16x8*>(
                As + (wm * 64 + i * 16 + rr) * 32 + slot8);
        #pragma unroll
        for (int j = 0; j < 4; ++j)
            bh[j] = *reinterpret_cast<const bf16x8*>(
                Bhs + (wn * 64 + j * 16 + rr) * 32 + slot8);
        if constexpr (DUAL) {
            const unsigned short* Bls = Bll + cur * 4096;
            #pragma unroll
            for (int j = 0; j < 4; ++j)
                bl[j] = *reinterpret_cast<const bf16x8*>(
                    Bls + (wn * 64 + j * 16 + rr) * 32 + slot8);
        }
        #pragma unroll
        for (int i = 0; i < 4; ++i)
            #pragma unroll
            for (int j = 0; j < 4; ++j) {
                acc[i][j] = __builtin_amdgcn_mfma_f32_16x16x32_bf16(af[i], bh[j], acc[i][j], 0, 0, 0);
                if constexpr (DUAL)
                    acl[i][j] = __builtin_amdgcn_mfma_f32_16x16x32_bf16(af[i], bl[j], acl[i][j], 0, 0, 0);
            }
        __syncthreads();
        cur ^= 1;
    }

    const int rg = lane >> 4;
    #pragma unroll
    for (int j = 0; j < 4; ++j) {
        const int col = n0 + wn * 64 + j * 16 + rr;
        const float bv = HAS_BIAS ? bias[col] : 0.f;
        #pragma unroll
        for (int i = 0; i < 4; ++i) {
            const int row0 = m0 + wm * 64 + i * 16 + rg * 4;
            #pragma unroll
            for (int r = 0; r < 4; ++r) {
                float val = acc[i][j][r] + bv;
                if constexpr (DUAL) val += acl[i][j][r];
                const size_t off = (size_t)(row0 + r) * N + col;
                if (OUT_BF16) reinterpret_cast<unsigned short*>(Cout)[off] = f2bf(val);
                else          reinterpret_cast<float*>(Cout)[off] = val;
            }
        }
    }
}

// ---------------- 256x256 NT GEMM, 8 waves, BK=64, 4-phase counted-vmcnt ----------------
// Main loop kt=0..NT-2 always prefetches (steady-state vmcnt arithmetic exact);
// last tile peeled into epilogue with no-prefetch waits (ph0 vmcnt(4), ph1 vmcnt(0)).
template<int OUT_BF16, int HAS_BIAS>
__global__ __launch_bounds__(512, 2) void k_gemm256(
    const unsigned short* __restrict__ A,
    const unsigned short* __restrict__ B,
    void* __restrict__ Cout,
    const float* __restrict__ bias)
{
    constexpr int K = 1024;
    constexpr int N = 1024;
    constexpr int NT = 16;
    __shared__ __align__(16) unsigned short lds[2][2][2][256][32];  // 128 KiB

    const int nwg = gridDim.x;
    const int bid = blockIdx.x;
    const int wg  = (bid & 7) * (nwg >> 3) + (bid >> 3);   // XCD swizzle (nwg%8==0)
    const int m0 = (wg >> 2) * 256;
    const int n0 = (wg & 3) * 256;

    const int tid = threadIdx.x;
    const int w = tid >> 6;
    const int lane = tid & 63;
    const int wr = w >> 2;
    const int wc = w & 3;

    const int srow = lane >> 2;
    const int sseg = lane & 3;
    const int sslot = sseg ^ ((srow >> 1) & 3);

    f32x4 acc[8][4] = {};

    // stage-units: 0=A(mh0) rg{0-3,8-11}, 1=B(nh0) rg{0,1,4,5,8,9,12,13},
    //              2=A(mh1) rg{4-7,12-15}, 3=B(nh1) rg{2,3,6,7,10,11,14,15}
    auto stage_unit = [&](int buf, int kt, int unit) {
        const int k0 = kt * 64;
        const int ab = unit & 1;
        const int sel = unit >> 1;
        #pragma unroll
        for (int j = 0; j < 2; ++j) {
            const int c  = (w << 1) | j;      // 0..15
            const int ks = c >> 3;
            const int c3 = c & 7;
            const int rg = ab ? (sel * 2 + (c3 & 1) + ((c3 >> 1) << 2))
                              : (sel * 4 + (c3 & 3) + ((c3 >> 2) << 3));
            const int row = rg * 16 + srow;
            const unsigned short* src =
                (ab ? B + (size_t)(n0 + row) * K : A + (size_t)(m0 + row) * K)
                + k0 + ks * 32 + sslot * 8;
            load_lds16(src, &lds[buf][ab][ks][rg * 16][0]);
        }
    };

    const int rr = lane & 15;
    const int rdslot = ((lane >> 4) ^ ((rr >> 1) & 3)) * 8;

    // prologue: tile 0, units in phase order (vmcnt arithmetic relies on this)
    stage_unit(0, 0, 0);
    stage_unit(0, 0, 1);
    stage_unit(0, 0, 2);
    stage_unit(0, 0, 3);

    bf16x8 a[4][2], b0[2][2], b1[2][2];
    int cur = 0;
    for (int kt = 0; kt < NT - 1; ++kt) {     // always prefetches tile kt+1
        const int nxt = cur ^ 1;

        // ---------- phase 0: quad (mh0, nh0); needs units 0,1 of tile kt ----------
        stage_unit(nxt, kt + 1, 0);
        asm volatile("s_waitcnt vmcnt(6)" ::: "memory");   // leaves 2,3[kt] + 0[kt+1]
        __builtin_amdgcn_s_barrier();
        __builtin_amdgcn_sched_barrier(0);
        #pragma unroll
        for (int i = 0; i < 4; ++i)
            #pragma unroll
            for (int ks = 0; ks < 2; ++ks)
                a[i][ks] = *reinterpret_cast<const bf16x8*>(
                    &lds[cur][0][ks][wr * 128 + i * 16 + rr][0] + rdslot);
        #pragma unroll
        for (int j = 0; j < 2; ++j)
            #pragma unroll
            for (int ks = 0; ks < 2; ++ks)
                b0[j][ks] = *reinterpret_cast<const bf16x8*>(
                    &lds[cur][1][ks][wc * 64 + j * 16 + rr][0] + rdslot);
        asm volatile("s_waitcnt lgkmcnt(0)" ::: "memory");
        __builtin_amdgcn_sched_barrier(0);
        __builtin_amdgcn_s_setprio(1);
        #pragma unroll
        for (int i = 0; i < 4; ++i)
            #pragma unroll
            for (int j = 0; j < 2; ++j)
                #pragma unroll
                for (int ks = 0; ks < 2; ++ks)
                    acc[i][j] = __builtin_amdgcn_mfma_f32_16x16x32_bf16(
                        a[i][ks], b0[j][ks], acc[i][j], 0, 0, 0);
        __builtin_amdgcn_s_setprio(0);

        // ---------- phase 1: quad (mh0, nh1); needs units 2,3 of tile kt ----------
        stage_unit(nxt, kt + 1, 1);
        asm volatile("s_waitcnt vmcnt(4)" ::: "memory");   // leaves 0,1[kt+1]
        __builtin_amdgcn_s_barrier();
        __builtin_amdgcn_sched_barrier(0);
        #pragma unroll
        for (int j = 0; j < 2; ++j)
            #pragma unroll
            for (int ks = 0; ks < 2; ++ks)
                b1[j][ks] = *reinterpret_cast<const bf16x8*>(
                    &lds[cur][1][ks][wc * 64 + 32 + j * 16 + rr][0] + rdslot);
        asm volatile("s_waitcnt lgkmcnt(0)" ::: "memory");
        __builtin_amdgcn_sched_barrier(0);
        __builtin_amdgcn_s_setprio(1);
        #pragma unroll
        for (int i = 0; i < 4; ++i)
            #pragma unroll
            for (int j = 0; j < 2; ++j)
                #pragma unroll
                for (int ks = 0; ks < 2; ++ks)
                    acc[i][2 + j] = __builtin_amdgcn_mfma_f32_16x16x32_bf16(
                        a[i][ks], b1[j][ks], acc[i][2 + j], 0, 0, 0);
        __builtin_amdgcn_s_setprio(0);

        // ---------- phase 2: quad (mh1, nh0); unit 2[kt] covered by ph1 wait ----------
        stage_unit(nxt, kt + 1, 2);
        __builtin_amdgcn_s_barrier();
        __builtin_amdgcn_sched_barrier(0);
        #pragma unroll
        for (int i = 0; i < 4; ++i)
            #pragma unroll
            for (int ks = 0; ks < 2; ++ks)
                a[i][ks] = *reinterpret_cast<const bf16x8*>(
                    &lds[cur][0][ks][wr * 128 + 64 + i * 16 + rr][0] + rdslot);
        asm volatile("s_waitcnt lgkmcnt(0)" ::: "memory");
        __builtin_amdgcn_sched_barrier(0);
        __builtin_amdgcn_s_setprio(1);
        #pragma unroll
        for (int i = 0; i < 4; ++i)
            #pragma unroll
            for (int j = 0; j < 2; ++j)
                #pragma unroll
                for (int ks = 0; ks < 2; ++ks)
                    acc[4 + i][j] = __builtin_amdgcn_mfma_f32_16x16x32_bf16(
                        a[i][ks], b0[j][ks], acc[4 + i][j], 0, 0, 0);
        __builtin_amdgcn_s_setprio(0);

        // ---------- phase 3: quad (mh1, nh1); regs only ----------
        stage_unit(nxt, kt + 1, 3);
        __builtin_amdgcn_s_barrier();          // all waves past ph2 lgkmcnt(0):
        __builtin_amdgcn_sched_barrier(0);     // buf[cur] reads done -> overwrite safe
        __builtin_amdgcn_s_setprio(1);
        #pragma unroll
        for (int i = 0; i < 4; ++i)
            #pragma unroll
            for (int j = 0; j < 2; ++j)
                #pragma unroll
                for (int ks = 0; ks < 2; ++ks)
                    acc[4 + i][2 + j] = __builtin_amdgcn_mfma_f32_16x16x32_bf16(
                        a[i][ks], b1[j][ks], acc[4 + i][2 + j], 0, 0, 0);
        __builtin_amdgcn_s_setprio(0);
        cur = nxt;
    }

    // ---------- epilogue: tile NT-1, no prefetch (outstanding = 8 at entry) ----------
    {
        asm volatile("s_waitcnt vmcnt(4)" ::: "memory");   // units 0,1 of last tile landed
        __builtin_amdgcn_s_barrier();
        __builtin_amdgcn_sched_barrier(0);
        #pragma unroll
        for (int i = 0; i < 4; ++i)
            #pragma unroll
            for (int ks = 0; ks < 2; ++ks)
                a[i][ks] = *reinterpret_cast<const bf16x8*>(
                    &lds[cur][0][ks][wr * 128 + i * 16 + rr][0] + rdslot);
        #pragma unroll
        for (int j = 0; j < 2; ++j)
            #pragma unroll
            for (int ks = 0; ks < 2; ++ks)
                b0[j][ks] = *reinterpret_cast<const bf16x8*>(
                    &lds[cur][1][ks][wc * 64 + j * 16 + rr][0] + rdslot);
        asm volatile("s_waitcnt lgkmcnt(0)" ::: "memory");
        __builtin_amdgcn_sched_barrier(0);
        __builtin_amdgcn_s_setprio(1);
        #pragma unroll
        for (int i = 0; i < 4; ++i)
            #pragma unroll
            for (int j = 0; j < 2; ++j)
                #pragma unroll
                for (int ks = 0; ks < 2; ++ks)
                    acc[i][j] = __builtin_amdgcn_mfma_f32_16x16x32_bf16(
                        a[i][ks], b0[j][ks], acc[i][j], 0, 0, 0);
        __builtin_amdgcn_s_setprio(0);

        asm volatile("s_waitcnt vmcnt(0)" ::: "memory");   // units 2,3 landed
        __builtin_amdgcn_s_barrier();                      // all waves fully staged
        __builtin_amdgcn_sched_barrier(0);
        #pragma unroll
        for (int j = 0; j < 2; ++j)
            #pragma unroll
            for (int ks = 0; ks < 2; ++ks)
                b1[j][ks] = *reinterpret_cast<const bf16x8*>(
                    &lds[cur][1][ks][wc * 64 + 32 + j * 16 + rr][0] + rdslot);
        asm volatile("s_waitcnt lgkmcnt(0)" ::: "memory");
        __builtin_amdgcn_sched_barrier(0);
        __builtin_amdgcn_s_setprio(1);
        #pragma unroll
        for (int i = 0; i < 4; ++i)
            #pragma unroll
            for (int j = 0; j < 2; ++j)
                #pragma unroll
                for (int ks = 0; ks < 2; ++ks)
                    acc[i][2 + j] = __builtin_amdgcn_mfma_f32_16x16x32_bf16(
                        a[i][ks], b1[j][ks], acc[i][2 + j], 0, 0, 0);
        __builtin_amdgcn_s_setprio(0);

        #pragma unroll
        for (int i = 0; i < 4; ++i)
            #pragma unroll
            for (int ks = 0; ks < 2; ++ks)
                a[i][ks] = *reinterpret_cast<const bf16x8*>(
                    &lds[cur][0][ks][wr * 128 + 64 + i * 16 + rr][0] + rdslot);
        asm volatile("s_waitcnt lgkmcnt(0)" ::: "memory");
        __builtin_amdgcn_sched_barrier(0);
        __builtin_amdgcn_s_setprio(1);
        #pragma unroll
        for (int i = 0; i < 4; ++i)
            #pragma unroll
            for (int j = 0; j < 2; ++j)
                #pragma unroll
                for (int ks = 0; ks < 2; ++ks) {
                    acc[4 + i][j] = __builtin_amdgcn_mfma_f32_16x16x32_bf16(
                        a[i][ks], b0[j][ks], acc[4 + i][j], 0, 0, 0);
                    acc[4 + i][2 + j] = __builtin_amdgcn_mfma_f32_16x16x32_bf16(
                        a[i][ks], b1[j][ks], acc[4 + i][2 + j], 0, 0, 0);
                }
        __builtin_amdgcn_s_setprio(0);
    }

    const int rg = lane >> 4;
    #pragma unroll
    for (int jj = 0; jj < 4; ++jj) {
        const int col = n0 + wc * 64 + jj * 16 + rr;
        const float bv = HAS_BIAS ? bias[col] : 0.f;
        #pragma unroll
        for (int i = 0; i < 8; ++i) {
            const int row0 = m0 + wr * 128 + i * 16 + rg * 4;
            #pragma unroll
            for (int r = 0; r < 4; ++r) {
                const float val = acc[i][jj][r] + bv;
                const size_t off = (size_t)(row0 + r) * N + col;
                if (OUT_BF16) reinterpret_cast<unsigned short*>(Cout)[off] = f2bf(val);
                else          reinterpret_cast<float*>(Cout)[off] = val;
            }
        }
    }
}

// ---------------- per-token HxH attention, one wave per token, full f32 ----------------
__global__ __launch_bounds__(256) void k_attn(
    const unsigned short* __restrict__ qp,
    const float* __restrict__ kp,
    const unsigned short* __restrict__ vp,
    const float* __restrict__ gamma,
    const float* __restrict__ beta,
    unsigned short* __restrict__ xout)
{
    __shared__ float ks[4][16 * 64];
    __shared__ float vs[4][16 * 64];

    const int w = threadIdx.x >> 6;
    const int lane = threadIdx.x & 63;
    const int token = blockIdx.x * 4 + w;
    const int b = token >> 11;
    const int n = token & 2047;
    const int kb = b & 3;

    const int h = lane >> 2;
    const int qd = lane & 3;
    const int d0 = qd * 16;

    const unsigned short* qptr = qp + (size_t)token * 1024 + h * 64 + d0;
    const float*          kptr = kp + (size_t)(kb * 2048 + n) * 1024 + h * 64 + d0;
    const unsigned short* vptr = vp + (size_t)(kb * 2048 + n) * 1024 + h * 64 + d0;

    float gm[16], bt[16];
    #pragma unroll
    for (int t = 0; t < 16; ++t) { gm[t] = gamma[d0 + t]; bt[t] = beta[d0 + t]; }

    float yq[16];
    {
        const uint4* p = reinterpret_cast<const uint4*>(qptr);
        const uint4 u0 = p[0], u1 = p[1];
        const uint32_t uu[8] = {u0.x, u0.y, u0.z, u0.w, u1.x, u1.y, u1.z, u1.w};
        float x[16]; float s = 0.f, sq = 0.f;
        #pragma unroll
        for (int t = 0; t < 8; ++t) {
            const float a = bf2f((unsigned short)(uu[t] & 0xffffu));
            const float c = bf2f((unsigned short)(uu[t] >> 16));
            x[2 * t] = a; x[2 * t + 1] = c;
            s += a + c; sq += a * a + c * c;
        }
        s  += __shfl_xor(s, 1);  s  += __shfl_xor(s, 2);
        sq += __shfl_xor(sq, 1); sq += __shfl_xor(sq, 2);
        const float mu = s * 0.015625f;
        const float var = sq * 0.015625f - mu * mu;
        const float inv = rsqrtf(var + 1e-5f);
        #pragma unroll
        for (int t = 0; t < 16; ++t)
            yq[t] = ((x[t] - mu) * inv * gm[t] + bt[t]) * 0.125f;
    }

    {
        const float4* p = reinterpret_cast<const float4*>(kptr);
        const float4 f0 = p[0], f1 = p[1], f2 = p[2], f3 = p[3];
        float x[16] = {f0.x, f0.y, f0.z, f0.w, f1.x, f1.y, f1.z, f1.w,
                       f2.x, f2.y, f2.z, f2.w, f3.x, f3.y, f3.z, f3.w};
        float s = 0.f, sq = 0.f;
        #pragma unroll
        for (int t = 0; t < 16; ++t) { s += x[t]; sq += x[t] * x[t]; }
        s  += __shfl_xor(s, 1);  s  += __shfl_xor(s, 2);
        sq += __shfl_xor(sq, 1); sq += __shfl_xor(sq, 2);
        const float mu = s * 0.015625f;
        const float var = sq * 0.015625f - mu * mu;
        const float inv = rsqrtf(var + 1e-5f);
        #pragma unroll
        for (int t = 0; t < 16; ++t)
            ks[w][h * 64 + d0 + t] = (x[t] - mu) * inv * gm[t] + bt[t];
    }

    {
        const uint4* p = reinterpret_cast<const uint4*>(vptr);
        const uint4 u0 = p[0], u1 = p[1];
        const uint32_t uu[8] = {u0.x, u0.y, u0.z, u0.w, u1.x, u1.y, u1.z, u1.w};
        #pragma unroll
        for (int t = 0; t < 8; ++t) {
            vs[w][h * 64 + d0 + 2 * t]     = bf2f((unsigned short)(uu[t] & 0xffffu));
            vs[w][h * 64 + d0 + 2 * t + 1] = bf2f((unsigned short)(uu[t] >> 16));
        }
    }
    __syncthreads();

    float S[16];
    #pragma unroll
    for (int g = 0; g < 16; ++g) {
        float p = 0.f;
        #pragma unroll
        for (int t = 0; t < 16; ++t) p += yq[t] * ks[w][g * 64 + d0 + t];
        p += __shfl_xor(p, 1);
        p += __shfl_xor(p, 2);
        S[g] = p;
    }

    float m = S[0];
    #pragma unroll
    for (int g = 1; g < 16; ++g) m = fmaxf(m, S[g]);
    float sum = 0.f;
    #pragma unroll
    for (int g = 0; g < 16; ++g) { S[g] = __expf(S[g] - m); sum += S[g]; }
    const float rs = 1.f / sum;
    #pragma unroll
    for (int g = 0; g < 16; ++g) S[g] *= rs;

    float xo[16] = {};
    #pragma unroll
    for (int g = 0; g < 16; ++g) {
        const float pg = S[g];
        #pragma unroll
        for (int t = 0; t < 16; ++t) xo[t] += pg * vs[w][g * 64 + d0 + t];
    }

    const size_t obase = (size_t)b * 2048 * 1024;
    const int row = h * 128 + (n >> 4);
    const int col = (n & 15) * 64 + d0;
    uint32_t pk[8];
    #pragma unroll
    for (int t = 0; t < 8; ++t)
        pk[t] = (uint32_t)f2bf(xo[2 * t]) | ((uint32_t)f2bf(xo[2 * t + 1]) << 16);
    uint4* dst = reinterpret_cast<uint4*>(xout + obase + (size_t)row * 1024 + col);
    uint4 lo; lo.x = pk[0]; lo.y = pk[1]; lo.z = pk[2]; lo.w = pk[3];
    uint4 hi; hi.x = pk[4]; hi.y = pk[5]; hi.z = pk[6]; hi.w = pk[7];
    dst[0] = lo; dst[1] = hi;
}

extern "C" void kernel_launch(void* const* d_in, const int* in_sizes, int n_in,
                              void* d_out, int out_size, void* d_ws, size_t ws_size,
                              hipStream_t stream) {
    const float* q     = (const float*)d_in[0];
    const float* k     = (const float*)d_in[1];
    const float* v     = (const float*)d_in[2];
    const float* Wq    = (const float*)d_in[3];
    const float* Wk    = (const float*)d_in[4];
    const float* Wv    = (const float*)d_in[5];
    const float* Wo    = (const float*)d_in[6];
    const float* bo    = (const float*)d_in[7];
    const float* gamma = (const float*)d_in[8];
    const float* beta  = (const float*)d_in[9];
    float* out = (float*)d_out;

    char* ws = (char*)d_ws;
    const size_t MB = 1024 * 1024;
    unsigned short* qb  = (unsigned short*)(ws + 0);
    unsigned short* xsc = (unsigned short*)(ws + 0);
    unsigned short* qpb = (unsigned short*)(ws + 64 * MB);
    float*          kpf = (float*)         (ws + 128 * MB);
    unsigned short* vpb = (unsigned short*)(ws + 160 * MB);
    unsigned short* kbb = (unsigned short*)(ws + 176 * MB);
    unsigned short* vbb = (unsigned short*)(ws + 176 * MB);
    unsigned short* Wkh = (unsigned short*)(ws + 192 * MB);
    unsigned short* Wkl = (unsigned short*)(ws + 194 * MB);
    unsigned short* Wvb = (unsigned short*)(ws + 196 * MB);
    unsigned short* Wqb = (unsigned short*)(ws + 198 * MB);
    unsigned short* Wob = (unsigned short*)(ws + 200 * MB);

    // ---- k path: dual (hi+lo) 128^2 GEMM into f32 kpf ----
    k_cvt_hl<<<512, 256, 0, stream>>>(Wk, Wkh, Wkl, 262144);
    k_cvt<<<1024, 256, 0, stream>>>(k, kbb, 2097152);
    k_gemm<0, 0, 1><<<512, 256, 0, stream>>>(kbb, Wkh, Wkl, kpf, nullptr, 8192);

    // ---- v path: 256^2 GEMM (vbb overwrites kbb after k-proj done) ----
    k_cvt<<<512, 256, 0, stream>>>(Wv, Wvb, 262144);
    k_cvt<<<1024, 256, 0, stream>>>(v, vbb, 2097152);
    k_gemm256<1, 0><<<128, 512, 0, stream>>>(vbb, Wvb, vpb, nullptr);

    // ---- q path: 256^2 counted-vmcnt GEMM ----
    k_cvt<<<512, 256, 0, stream>>>(Wq, Wqb, 262144);
    k_cvt<<<2048, 256, 0, stream>>>(q, qb, 8388608);
    k_gemm256<1, 0><<<512, 512, 0, stream>>>(qb, Wqb, qpb, nullptr);

    // ---- attention (full f32 middle), scrambled bf16 out over qb ----
    k_attn<<<8192, 256, 0, stream>>>(qpb, kpf, vpb, gamma, beta, xsc);

    // ---- out path: 256^2 GEMM, f32 + bias into d_out ----
    k_cvt<<<512, 256, 0, stream>>>(Wo, Wob, 262144);
    k_gemm256<0, 1><<<512, 512, 0, stream>>>(xsc, Wob, out, bo);
}